// Round 3
// baseline (2694.217 us; speedup 1.0000x reference)
//
#include <hip/hip_runtime.h>
#include <hip/hip_bf16.h>
#include <math.h>

typedef __attribute__((ext_vector_type(8))) short short8;
typedef __attribute__((ext_vector_type(4))) float f32x4;
typedef __hip_bfloat16 bf16;

#define BB 2
#define TT 16
#define SSQ 257
#define DIMD 512
#define NROWS 8224          // B*T*S
#define DII 1365
#define DI2 2730
#define FNPAD 2816          // ff_in N padded (22*128), block-16 interleaved a/g
#define GLULD 1408          // glu row stride / ff_out K (44*32)
#define SKP 288             // padded key count for space attn
#define EPSR 1.1920929e-07f

__device__ __forceinline__ void async16(const void* g, const void* l) {
    __builtin_amdgcn_global_load_lds(
        (const __attribute__((address_space(1))) void*)g,
        (__attribute__((address_space(3))) void*)l, 16, 0, 0);
}

__device__ __forceinline__ short f2bfs(float x) {
    bf16 h = __float2bfloat16(x);
    return *reinterpret_cast<short*>(&h);
}

// fast exact-gelu: a * g * Phi(g), erf via A&S 7.1.26 (abs err 1.5e-7)
__device__ __forceinline__ float glu_fast(float a, float g) {
    float x = g * 0.70710678118654752f;
    float ax = fabsf(x);
    float t = __builtin_amdgcn_rcpf(__builtin_fmaf(0.3275911f, ax, 1.f));
    float p = t * (0.254829592f + t * (-0.284496736f + t * (1.421413741f
              + t * (-1.453152027f + t * 1.061405429f))));
    float erfv = 1.f - p * __expf(-ax * ax);
    erfv = (x < 0.f) ? -erfv : erfv;
    return a * 0.5f * g * (1.f + erfv);
}

// ---------------- batched per-layer weight transpose fp32->bf16 ----------------
// win interleave: a_j -> col (j>>4)*32 + (j&15); g_j -> col (j>>4)*32 + 16 + (j&15)
// (a and g for output j land in the same lane, adjacent 16-col frags in the GEMM)
__global__ void wtrans_layer(const float* __restrict__ wq, const float* __restrict__ wk,
                             const float* __restrict__ wv, const float* __restrict__ wo,
                             const float* __restrict__ win, const float* __restrict__ wout,
                             bf16* __restrict__ dqkv, bf16* __restrict__ dwo,
                             bf16* __restrict__ dwin, bf16* __restrict__ dwout) {
    __shared__ float tile[32][33];
    int bid = blockIdx.x;
    const float* src; bf16* dst; int K, M, Kpad, interleave = 0, local;
    if (bid < 512)       { src = wq;   dst = dqkv;            K = 512;  M = 1024; Kpad = 512;  local = bid; }
    else if (bid < 768)  { src = wk;   dst = dqkv + 1024*512; K = 512;  M = 512;  Kpad = 512;  local = bid - 512; }
    else if (bid < 1024) { src = wv;   dst = dqkv + 1536*512; K = 512;  M = 512;  Kpad = 512;  local = bid - 768; }
    else if (bid < 1536) { src = wo;   dst = dwo;             K = 1024; M = 512;  Kpad = 1024; local = bid - 1024; }
    else if (bid < 2944) { src = win;  dst = dwin;            K = 512;  M = 2730; Kpad = 512;  local = bid - 1536; interleave = 1; }
    else                 { src = wout; dst = dwout;           K = 1365; M = 512;  Kpad = 1408; local = bid - 2944; }
    int tilesx = Kpad >> 5;
    int k0 = (local % tilesx) * 32, m0 = (local / tilesx) * 32;
    int tx = threadIdx.x & 31, ty = threadIdx.x >> 5;
    #pragma unroll
    for (int i = 0; i < 4; ++i) {
        int k = k0 + ty + 8 * i, m = m0 + tx;
        tile[ty + 8 * i][tx] = (k < K && m < M) ? src[(size_t)k * M + m] : 0.f;
    }
    __syncthreads();
    #pragma unroll
    for (int i = 0; i < 4; ++i) {
        int n = m0 + ty + 8 * i, k = k0 + tx;
        int nd = n;
        if (interleave) {
            if (n < DII)        nd = ((n >> 4) << 5) + (n & 15);
            else if (n < DI2) { int m = n - DII; nd = ((m >> 4) << 5) + 16 + (m & 15); }
            else              { int q = n - DI2; int j = DII + (q >> 1);
                                nd = ((j >> 4) << 5) + ((q & 1) << 4) + (j & 15); }
        }
        dst[(size_t)nd * Kpad + k] = __float2bfloat16(tile[tx][ty + 8 * i]);
    }
}

// ---------------- RMSNorm: one wave per row, float4 loads, shuffle reduce ----------------
template<int BF16OUT>
__global__ __launch_bounds__(256)
void rms_kernel(const float* __restrict__ x, const float* __restrict__ w,
                void* __restrict__ out, int perm) {
    int wave = threadIdx.x >> 6, lane = threadIdx.x & 63;
    int r = blockIdx.x * 4 + wave;
    int src = r;
    if (perm) {
        int t = r & 15; int rs = r >> 4; int s = rs % SSQ; int b = rs / SSQ;
        src = (b * TT + t) * SSQ + s;
    }
    const float4* xr = (const float4*)(x + (size_t)src * DIMD) + lane * 2;
    float4 a = xr[0], c = xr[1];
    float ss = a.x*a.x + a.y*a.y + a.z*a.z + a.w*a.w
             + c.x*c.x + c.y*c.y + c.z*c.z + c.w*c.w;
    ss += __shfl_xor(ss, 1);  ss += __shfl_xor(ss, 2);  ss += __shfl_xor(ss, 4);
    ss += __shfl_xor(ss, 8);  ss += __shfl_xor(ss, 16); ss += __shfl_xor(ss, 32);
    float sc = rsqrtf(ss * (1.f / DIMD) + EPSR);
    const float4* wr = (const float4*)w + lane * 2;
    float4 wa = wr[0], wb = wr[1];
    if (BF16OUT) {
        short8 v;
        v[0] = f2bfs(a.x * sc * wa.x); v[1] = f2bfs(a.y * sc * wa.y);
        v[2] = f2bfs(a.z * sc * wa.z); v[3] = f2bfs(a.w * sc * wa.w);
        v[4] = f2bfs(c.x * sc * wb.x); v[5] = f2bfs(c.y * sc * wb.y);
        v[6] = f2bfs(c.z * sc * wb.z); v[7] = f2bfs(c.w * sc * wb.w);
        *(short8*)((bf16*)out + (size_t)r * DIMD + lane * 8) = v;
    } else {
        float4* o = (float4*)((float*)out + (size_t)r * DIMD) + lane * 2;
        float4 o0 = {a.x * sc * wa.x, a.y * sc * wa.y, a.z * sc * wa.z, a.w * sc * wa.w};
        float4 o1 = {c.x * sc * wb.x, c.y * sc * wb.y, c.z * sc * wb.z, c.w * sc * wb.w};
        o[0] = o0; o[1] = o1;
    }
}

// ---------------- MFMA bf16 GEMM: C[nrow,M] = A[nrow,K] @ Bt[M,K]^T ----------------
// TM x 128 tile, BK=32, double-buffered LDS (1 barrier/iter), conflict-free
// granule swizzle kc' = kc ^ ((m>>1)&3). 4 waves, MI = TM/32 m-frags per wave.
// EPI: 1 = qkv + fused l2norm/gamma/rotary; 2 = glu (block-16 interleaved a/g,
// no shuffles, all lanes active); 3 = fp32 accumulate.
template<int EPI, int PERM, int TM>
__global__ __launch_bounds__(256)
void mfma_gemm(const bf16* __restrict__ A, int lda,
               const bf16* __restrict__ Bt, int ldb,
               const float* __restrict__ bias,
               void* __restrict__ C, int ldc, int Mstore,
               int nrow, int K,
               const float* __restrict__ qg, const float* __restrict__ kg, int rotary) {
    constexpr int MI = TM / 32;                 // m-frags per wave (8, 4 or 2)
    constexpr int ALW = TM / 64;                // A-stage loads per wave
    __shared__ __align__(16) short lds_a[2][TM * 32];
    __shared__ __align__(16) short lds_b[2][128 * 32];
    int tid = threadIdx.x;
    int wave = tid >> 6, lane = tid & 63;
    int quad = lane >> 4, l16 = lane & 15;
    int m0 = blockIdx.y * TM, n0 = blockIdx.x * 128;
    int wm = (wave & 1) * (TM / 2), wn = (wave >> 1) * 64;
    f32x4 zero4 = {0.f, 0.f, 0.f, 0.f};
    f32x4 acc[MI][4];
    #pragma unroll
    for (int i = 0; i < MI; ++i)
        #pragma unroll
        for (int j = 0; j < 4; ++j) acc[i][j] = zero4;

    const short* Ap = (const short*)A;
    const short* Bp = (const short*)Bt;
    // staging granule -> global pointer (granule g holds X[m=g>>2][kc=(g&3)^((g>>3)&3)])
    auto aptr = [&](int g) {
        int m = g >> 2, kc = (g & 3) ^ ((g >> 3) & 3);
        int r = m0 + m; if (r >= nrow) r = nrow - 1;
        return Ap + (size_t)r * lda + kc * 8;
    };
    auto bptr = [&](int g) {
        int m = g >> 2, kc = (g & 3) ^ ((g >> 3) & 3);
        return Bp + (size_t)(n0 + m) * ldb + kc * 8;
    };
    const short* gA[ALW]; int aoff[ALW];
    #pragma unroll
    for (int j = 0; j < ALW; ++j) {
        gA[j] = aptr(wave * TM + j * 64 + lane);
        aoff[j] = (wave * TM + j * 64) * 8;
    }
    const short* gB0 = bptr(wave * 128 + lane);
    const short* gB1 = bptr(wave * 128 + 64 + lane);
    int boff0 = (wave * 128) * 8, boff1 = (wave * 128 + 64) * 8;

    auto stage = [&](int buf, int kt) {
        int ko = kt * 32;
        #pragma unroll
        for (int j = 0; j < ALW; ++j)
            async16(gA[j] + ko, &lds_a[buf][aoff[j]]);
        async16(gB0 + ko, &lds_b[buf][boff0]);
        async16(gB1 + ko, &lds_b[buf][boff1]);
    };

    int nk = K >> 5;
    stage(0, 0);
    for (int kt = 0; kt < nk; ++kt) {
        int buf = kt & 1;
        __syncthreads();                       // stage(kt) complete
        if (kt + 1 < nk) stage(buf ^ 1, kt + 1);
        short8 af[MI], bfr[4];
        #pragma unroll
        for (int mi = 0; mi < MI; ++mi) {
            int m = wm + mi * 16 + l16;
            af[mi] = *(const short8*)&lds_a[buf][(m * 4 + (quad ^ ((m >> 1) & 3))) * 8];
        }
        #pragma unroll
        for (int nj = 0; nj < 4; ++nj) {
            int n = wn + nj * 16 + l16;
            bfr[nj] = *(const short8*)&lds_b[buf][(n * 4 + (quad ^ ((n >> 1) & 3))) * 8];
        }
        #pragma unroll
        for (int mi = 0; mi < MI; ++mi)
            #pragma unroll
            for (int nj = 0; nj < 4; ++nj)
                acc[mi][nj] = __builtin_amdgcn_mfma_f32_16x16x32_bf16(
                    af[mi], bfr[nj], acc[mi][nj], 0, 0, 0);
    }

    if constexpr (EPI == 1) {
        // qkv output: cols wn..wn+63 = exactly one head.
        int head = (n0 + wn) >> 6;          // 0..15 q, 16..23 k, 24..31 v
        float gl0 = 0.f, gl1 = 0.f, gl2 = 0.f, gl3 = 0.f, inv0 = 0.f, inv1 = 0.f;
        if (head < 24) {
            const float* g = head < 16 ? qg + head * 64 : kg + (head - 16) * 64;
            gl0 = (g[l16] + 1.f) * 8.f;
            gl1 = (g[16 + l16] + 1.f) * 8.f;
            gl2 = (g[32 + l16] + 1.f) * 8.f;
            gl3 = (g[48 + l16] + 1.f) * 8.f;
            if (rotary) {
                inv0 = __expf(-(float)l16 * 0.28782313662425572f);        // ln(1e4)/32
                inv1 = __expf(-(float)(l16 + 16) * 0.28782313662425572f);
            }
        }
        #pragma unroll
        for (int mi = 0; mi < MI; ++mi) {
            #pragma unroll
            for (int e = 0; e < 4; ++e) {
                int row = m0 + wm + mi * 16 + quad * 4 + e;
                float v0 = acc[mi][0][e], v1 = acc[mi][1][e];
                float v2 = acc[mi][2][e], v3 = acc[mi][3][e];
                if (head < 24) {
                    float ss = v0 * v0 + v1 * v1 + v2 * v2 + v3 * v3;
                    ss += __shfl_xor(ss, 1); ss += __shfl_xor(ss, 2);
                    ss += __shfl_xor(ss, 4); ss += __shfl_xor(ss, 8);
                    float invn = 1.f / fmaxf(sqrtf(ss), 1e-12f);
                    v0 *= invn * gl0; v1 *= invn * gl1;
                    v2 *= invn * gl2; v3 *= invn * gl3;
                    if (rotary) {
                        float t = (float)(row & 15);
                        float a0 = t * inv0, a1 = t * inv1;
                        float c0 = __cosf(a0), s0 = __sinf(a0);
                        float c1 = __cosf(a1), s1 = __sinf(a1);
                        float n0v = v0 * c0 - v2 * s0;
                        float n1v = v1 * c1 - v3 * s1;
                        float n2v = v2 * c0 + v0 * s0;
                        float n3v = v3 * c1 + v1 * s1;
                        v0 = n0v; v1 = n1v; v2 = n2v; v3 = n3v;
                    }
                }
                if (row < nrow) {
                    bf16* p = (bf16*)C + (size_t)row * ldc + n0 + wn + l16;
                    p[0]  = __float2bfloat16(v0);
                    p[16] = __float2bfloat16(v1);
                    p[32] = __float2bfloat16(v2);
                    p[48] = __float2bfloat16(v3);
                }
            }
        }
    } else if constexpr (EPI == 2) {
        // block-16 interleave: nj 0/2 hold a, nj 1/3 hold g for the same j in
        // the SAME lane. j = (n0+wn)/2 + (nj>>1)*16 + l16. All lanes active.
        int jbase = (n0 + wn) >> 1;
        int j0 = jbase + l16, j1 = jbase + 16 + l16;
        float ba0 = (j0 < DII) ? bias[j0] : 0.f;
        float bg0 = (j0 < DII) ? bias[DII + j0] : 0.f;
        float ba1 = (j1 < DII) ? bias[j1] : 0.f;
        float bg1 = (j1 < DII) ? bias[DII + j1] : 0.f;
        #pragma unroll
        for (int mi = 0; mi < MI; ++mi) {
            #pragma unroll
            for (int e = 0; e < 4; ++e) {
                int row = m0 + wm + mi * 16 + quad * 4 + e;
                if (row < nrow) {
                    bf16* cr = (bf16*)C + (size_t)row * ldc;
                    cr[j0] = __float2bfloat16(
                        glu_fast(acc[mi][0][e] + ba0, acc[mi][1][e] + bg0));
                    cr[j1] = __float2bfloat16(
                        glu_fast(acc[mi][2][e] + ba1, acc[mi][3][e] + bg1));
                }
            }
        }
    } else {
        #pragma unroll
        for (int mi = 0; mi < MI; ++mi) {
            #pragma unroll
            for (int e = 0; e < 4; ++e) {
                int row = m0 + wm + mi * 16 + quad * 4 + e;
                if (row >= nrow) continue;
                int orow = row;
                if (PERM) {
                    int t = row & 15; int rs = row >> 4; int s = rs % SSQ; int b = rs / SSQ;
                    orow = (b * TT + t) * SSQ + s;
                }
                #pragma unroll
                for (int nj = 0; nj < 4; ++nj) {
                    int col = n0 + wn + nj * 16 + l16;
                    if (col >= Mstore) continue;
                    float v = acc[mi][nj][e];
                    if (bias) v += bias[col];
                    ((float*)C)[(size_t)orow * ldc + col] += v;
                }
            }
        }
    }
}

// ---------------- V transpose for PV MFMA: vt[bt*8+kh][64][SKP] bf16 ----------------
__global__ void vtrans_kernel(const bf16* __restrict__ qkv, bf16* __restrict__ vt) {
    int bkh = blockIdx.x;          // bt*8 + kh
    int kc = blockIdx.y;           // key chunk of 32
    int bt = bkh >> 3, kh = bkh & 7;
    int tid = threadIdx.x;
    #pragma unroll
    for (int i = 0; i < 8; ++i) {
        int idx = tid + 256 * i;   // 0..2047
        int kl = idx >> 6;         // key local
        int d = idx & 63;
        int key = kc * 32 + kl;
        float v = 0.f;
        if (key < SSQ)
            v = __bfloat162float(qkv[((size_t)(bt * SSQ + key)) * 2048 + 1536 + kh * 64 + d]);
        vt[((size_t)bkh * 64 + d) * SKP + key] = __float2bfloat16(v);
    }
}

// ---------------- space attention: S^T in registers, K staged in LDS ----------------
__global__ __launch_bounds__(256)
void space_attn_kernel(const bf16* __restrict__ qkv, const bf16* __restrict__ vt,
                       bf16* __restrict__ ob) {
    __shared__ __align__(16) short kls[272 * 8 * 8];   // granule (key,c): K[key][8*(c^(key&7))..+8)
    int qt = blockIdx.x, qh = blockIdx.y, bt = blockIdx.z;
    int kh = qh >> 1;
    int tid = threadIdx.x, wave = tid >> 6, lane = tid & 63;
    int quad = lane >> 4, l16 = lane & 15;
    int q0w = qt * 64 + wave * 16;
    int q = q0w + l16;
    int qc = q > 256 ? 256 : q;
    const short* qbase = (const short*)qkv + (size_t)bt * SSQ * 2048;

    // stage K: 272 keys * 8 chunks = 2176 granules of 16B, 64/wave-iter
    const short* kgbase = qbase + 1024 + kh * 64;
    #pragma unroll
    for (int it = 0; it < 9; ++it) {
        int u = it * 4 + wave;
        if (u < 34) {
            int g = u * 64 + lane;
            int key = g >> 3, ch = g & 7;
            int srck = key < SSQ ? key : 256;
            async16(kgbase + (size_t)srck * 2048 + (ch ^ (key & 7)) * 8,
                    &kls[u * 512]);
        }
    }

    const short* qp = qbase + (size_t)qc * 2048 + qh * 64;
    short8 bq0 = *(const short8*)(qp + quad * 8);
    short8 bq1 = *(const short8*)(qp + 32 + quad * 8);
    __syncthreads();   // drains vmcnt: K staged

    f32x4 zero4 = {0.f, 0.f, 0.f, 0.f};
    f32x4 sc[18];
    float sum = 0.f;
    int c0 = quad ^ (l16 & 7);   // key&7 == l16&7 since kt*16 % 8 == 0
    #pragma unroll
    for (int kt = 0; kt < 17; ++kt) {
        int key = kt * 16 + l16;
        short8 ak0 = *(const short8*)&kls[(key * 8 + c0) * 8];
        short8 ak1 = *(const short8*)&kls[(key * 8 + (c0 ^ 4)) * 8];
        f32x4 cc = zero4;
        cc = __builtin_amdgcn_mfma_f32_16x16x32_bf16(ak0, bq0, cc, 0, 0, 0);
        cc = __builtin_amdgcn_mfma_f32_16x16x32_bf16(ak1, bq1, cc, 0, 0, 0);
        #pragma unroll
        for (int e = 0; e < 4; ++e) {
            float x = cc[e] * 0.0025f;           // s/50, s = dot/8
            float x2 = x * x;
            float v = cc[e] * 0.125f * (1.f + x2 * (-0.3333333333f + x2 * 0.1333333333f));
            float p = __expf(v);                 // v in [-8.1, 8.1]: no overflow
            if (kt == 16) {
                bool valid = (e == 0) && (quad == 0) && (q == 256);
                p = valid ? p : 0.f;
            }
            cc[e] = p;
            sum += p;
        }
        sc[kt] = cc;
    }
    #pragma unroll
    for (int e = 0; e < 4; ++e) sc[17][e] = 0.f;
    sum += __shfl_xor(sum, 16);
    sum += __shfl_xor(sum, 32);
    float inv = __builtin_amdgcn_rcpf(sum);
    f32x4 inv4;
    #pragma unroll
    for (int e = 0; e < 4; ++e) inv4[e] = __shfl(inv, quad * 4 + e);

    f32x4 oacc[4];
    #pragma unroll
    for (int nt = 0; nt < 4; ++nt) oacc[nt] = zero4;
    const short* vbp = (const short*)vt + ((size_t)(bt * 8 + kh) * 64 + l16) * SKP;
    #pragma unroll
    for (int c8 = 0; c8 < 9; ++c8) {
        short8 pb;
        #pragma unroll
        for (int j = 0; j < 8; ++j) {
            int src_lane = ((quad & 1) * 2 + (j >> 2)) * 16 + l16;
            float v0 = __shfl(sc[2 * c8][j & 3], src_lane);
            float v1 = __shfl(sc[2 * c8 + 1][j & 3], src_lane);
            pb[j] = f2bfs(quad < 2 ? v0 : v1);
        }
        #pragma unroll
        for (int nt = 0; nt < 4; ++nt) {
            short8 av = *(const short8*)(vbp + (size_t)(nt * 16) * SKP + c8 * 32 + quad * 8);
            oacc[nt] = __builtin_amdgcn_mfma_f32_16x16x32_bf16(pb, av, oacc[nt], 0, 0, 0);
        }
    }

    #pragma unroll
    for (int e = 0; e < 4; ++e) {
        int qq = q0w + quad * 4 + e;
        if (qq <= 256) {
            bf16* op = ob + ((size_t)(bt * SSQ + qq)) * 1024 + qh * 64 + l16;
            float s = inv4[e];
            op[0]  = __float2bfloat16(oacc[0][e] * s);
            op[16] = __float2bfloat16(oacc[1][e] * s);
            op[32] = __float2bfloat16(oacc[2][e] * s);
            op[48] = __float2bfloat16(oacc[3][e] * s);
        }
    }
}

// ---------------- time attention (n=16, causal): one block per (b*s, qh) ----------------
__global__ void time_attn_kernel(const bf16* __restrict__ qkv, bf16* __restrict__ ob) {
    __shared__ float qs[16][65], ks[16][65], ps[16][17];
    int bs = blockIdx.x, qh = blockIdx.y, kh = qh >> 1;
    int tid = threadIdx.x;
    size_t rowbase = (size_t)bs * 16;
    #pragma unroll
    for (int i = 0; i < 4; ++i) {
        int idx = tid + 256 * i;
        int r = idx >> 6, d = idx & 63;
        qs[r][d] = __bfloat162float(qkv[(rowbase + r) * 2048 + qh * 64 + d]);
        ks[r][d] = __bfloat162float(qkv[(rowbase + r) * 2048 + 1024 + kh * 64 + d]);
    }
    __syncthreads();
    int i = tid >> 4, j = tid & 15;
    float dot = 0.f;
    #pragma unroll 16
    for (int d = 0; d < 64; ++d) dot += qs[i][d] * ks[j][d];
    float s = dot * 0.125f;
    // softclamp via 5th-order tanh poly (|s/50| <= 0.162); bounded -> no max pass
    float x = s * 0.02f;
    float x2 = x * x;
    float v = s * (1.f + x2 * (-0.3333333333f + x2 * 0.1333333333f));
    float p = (j > i) ? 0.f : __expf(v);
    float sum = p;
    sum += __shfl_xor(sum, 1);
    sum += __shfl_xor(sum, 2);
    sum += __shfl_xor(sum, 4);
    sum += __shfl_xor(sum, 8);
    ps[i][j] = p * __builtin_amdgcn_rcpf(sum);
    __syncthreads();
    #pragma unroll
    for (int ii = 0; ii < 4; ++ii) {
        int idx = tid + 256 * ii;
        int r = idx >> 6, d = idx & 63;
        float acc = 0.f;
        #pragma unroll
        for (int jj = 0; jj < 16; ++jj)
            acc += ps[r][jj] * __bfloat162float(qkv[(rowbase + jj) * 2048 + 1536 + kh * 64 + d]);
        ob[(rowbase + r) * 1024 + qh * 64 + d] = __float2bfloat16(acc);
    }
}

// ---------------- host-side launch ----------------
extern "C" void kernel_launch(void* const* d_in, const int* in_sizes, int n_in,
                              void* d_out, int out_size, void* d_ws, size_t ws_size,
                              hipStream_t stream) {
    const float* tokens      = (const float*)d_in[0];
    const float* attn_norm_w = (const float*)d_in[1];
    const float* Wq          = (const float*)d_in[2];
    const float* Wk          = (const float*)d_in[3];
    const float* Wv          = (const float*)d_in[4];
    const float* q_gamma     = (const float*)d_in[5];
    const float* k_gamma     = (const float*)d_in[6];
    const float* Wo          = (const float*)d_in[7];
    const float* ff_norm_w   = (const float*)d_in[8];
    const float* W_in        = (const float*)d_in[9];
    const float* b_in        = (const float*)d_in[10];
    const float* W_out       = (const float*)d_in[11];
    const float* b_out       = (const float*)d_in[12];
    const float* final_w     = (const float*)d_in[13];

    float* x = (float*)d_out;
    char* ws = (char*)d_ws;

    bf16* wtqkv = (bf16*)ws;                     // [2048][512]
    bf16* wto   = wtqkv + 2048 * 512;            // [512][1024]
    bf16* wtin  = wto   + 512 * 1024;            // [2816][512] interleaved
    bf16* wtout = wtin  + 2816 * 512;            // [512][1408]
    size_t off = (size_t)(2048*512 + 512*1024 + 2816*512 + 512*1408) * 2;
    bf16* h = (bf16*)(ws + off);                 // [N][512]
    off += (size_t)NROWS * 512 * 2;
    char* region = ws + off;
    bf16* qkv = (bf16*)region;                               // [N][2048]
    bf16* glu = (bf16*)region;                               // [N][1408] (FF alias)
    bf16* vt  = (bf16*)(region + (size_t)NROWS * 2048 * 2);  // [256][64][288]
    bf16* ob  = (bf16*)(region + (size_t)NROWS * 2048 * 2 + (size_t)256*64*SKP*2);  // [N][1024]

    hipMemcpyAsync(x, tokens, (size_t)NROWS * 512 * 4, hipMemcpyDeviceToDevice, stream);

    for (int l = 0; l < 8; ++l) {
        int is_time = ((l + 1) % 4 == 0) ? 1 : 0;
        wtrans_layer<<<3648, 256, 0, stream>>>(
            Wq + (size_t)l * 512 * 1024, Wk + (size_t)l * 512 * 512,
            Wv + (size_t)l * 512 * 512, Wo + (size_t)l * 1024 * 512,
            W_in + (size_t)l * 512 * DI2, W_out + (size_t)l * DII * 512,
            wtqkv, wto, wtin, wtout);

        // ---- attention block ----
        rms_kernel<1><<<2056, 256, 0, stream>>>(x, attn_norm_w + (size_t)l * 512, h, is_time);
        mfma_gemm<1, 0, 256><<<dim3(16, 33), 256, 0, stream>>>(
            h, 512, wtqkv, 512, nullptr, qkv, 2048, 2048, NROWS, 512,
            q_gamma + (size_t)l * 1024, k_gamma + (size_t)l * 512, is_time);
        if (is_time) {
            time_attn_kernel<<<dim3(514, 16), 256, 0, stream>>>(qkv, ob);
            mfma_gemm<3, 1, 64><<<dim3(4, 129), 256, 0, stream>>>(
                ob, 1024, wto, 1024, nullptr, x, 512, 512, NROWS, 1024, nullptr, nullptr, 0);
        } else {
            vtrans_kernel<<<dim3(256, 9), 256, 0, stream>>>(qkv, vt);
            space_attn_kernel<<<dim3(5, 16, 32), 256, 0, stream>>>(qkv, vt, ob);
            mfma_gemm<3, 0, 64><<<dim3(4, 129), 256, 0, stream>>>(
                ob, 1024, wto, 1024, nullptr, x, 512, 512, NROWS, 1024, nullptr, nullptr, 0);
        }

        // ---- feed-forward block ----
        rms_kernel<1><<<2056, 256, 0, stream>>>(x, ff_norm_w + (size_t)l * 512, h, 0);
        mfma_gemm<2, 0, 256><<<dim3(22, 33), 256, 0, stream>>>(
            h, 512, wtin, 512, b_in + (size_t)l * DI2, glu, GLULD, FNPAD, NROWS, 512,
            nullptr, nullptr, 0);
        mfma_gemm<3, 0, 64><<<dim3(4, 129), 256, 0, stream>>>(
            glu, GLULD, wtout, GLULD, b_out + (size_t)l * 512, x, 512, 512, NROWS, GLULD,
            nullptr, nullptr, 0);
    }

    rms_kernel<0><<<2056, 256, 0, stream>>>(x, final_w, x, 0);
}

// Round 4
// 2341.815 us; speedup vs baseline: 1.1505x; 1.1505x over previous
//
#include <hip/hip_runtime.h>
#include <hip/hip_bf16.h>
#include <math.h>

typedef __attribute__((ext_vector_type(8))) short short8;
typedef __attribute__((ext_vector_type(4))) float f32x4;
typedef __hip_bfloat16 bf16;

#define BB 2
#define TT 16
#define SSQ 257
#define DIMD 512
#define NROWS 8224          // B*T*S
#define DII 1365
#define DI2 2730
#define FNPAD 2816          // ff_in N padded (22*128), block-16 interleaved a/g
#define GLULD 1408          // glu row stride / ff_out K (44*32)
#define SKP 288             // padded key count for space attn
#define EPSR 1.1920929e-07f

__device__ __forceinline__ void async16(const void* g, const void* l) {
    __builtin_amdgcn_global_load_lds(
        (const __attribute__((address_space(1))) void*)g,
        (__attribute__((address_space(3))) void*)l, 16, 0, 0);
}

__device__ __forceinline__ short f2bfs(float x) {
    bf16 h = __float2bfloat16(x);
    return *reinterpret_cast<short*>(&h);
}

// fast exact-gelu: a * g * Phi(g), erf via A&S 7.1.26 (abs err 1.5e-7)
__device__ __forceinline__ float glu_fast(float a, float g) {
    float x = g * 0.70710678118654752f;
    float ax = fabsf(x);
    float t = __builtin_amdgcn_rcpf(__builtin_fmaf(0.3275911f, ax, 1.f));
    float p = t * (0.254829592f + t * (-0.284496736f + t * (1.421413741f
              + t * (-1.453152027f + t * 1.061405429f))));
    float erfv = 1.f - p * __expf(-ax * ax);
    erfv = (x < 0.f) ? -erfv : erfv;
    return a * 0.5f * g * (1.f + erfv);
}

// ---------------- batched per-layer weight transpose fp32->bf16 ----------------
// win interleave: a_j -> col (j>>4)*32 + (j&15); g_j -> col (j>>4)*32 + 16 + (j&15)
__global__ void wtrans_layer(const float* __restrict__ wq, const float* __restrict__ wk,
                             const float* __restrict__ wv, const float* __restrict__ wo,
                             const float* __restrict__ win, const float* __restrict__ wout,
                             bf16* __restrict__ dqkv, bf16* __restrict__ dwo,
                             bf16* __restrict__ dwin, bf16* __restrict__ dwout) {
    __shared__ float tile[32][33];
    int bid = blockIdx.x;
    const float* src; bf16* dst; int K, M, Kpad, interleave = 0, local;
    if (bid < 512)       { src = wq;   dst = dqkv;            K = 512;  M = 1024; Kpad = 512;  local = bid; }
    else if (bid < 768)  { src = wk;   dst = dqkv + 1024*512; K = 512;  M = 512;  Kpad = 512;  local = bid - 512; }
    else if (bid < 1024) { src = wv;   dst = dqkv + 1536*512; K = 512;  M = 512;  Kpad = 512;  local = bid - 768; }
    else if (bid < 1536) { src = wo;   dst = dwo;             K = 1024; M = 512;  Kpad = 1024; local = bid - 1024; }
    else if (bid < 2944) { src = win;  dst = dwin;            K = 512;  M = 2730; Kpad = 512;  local = bid - 1536; interleave = 1; }
    else                 { src = wout; dst = dwout;           K = 1365; M = 512;  Kpad = 1408; local = bid - 2944; }
    int tilesx = Kpad >> 5;
    int k0 = (local % tilesx) * 32, m0 = (local / tilesx) * 32;
    int tx = threadIdx.x & 31, ty = threadIdx.x >> 5;
    #pragma unroll
    for (int i = 0; i < 4; ++i) {
        int k = k0 + ty + 8 * i, m = m0 + tx;
        tile[ty + 8 * i][tx] = (k < K && m < M) ? src[(size_t)k * M + m] : 0.f;
    }
    __syncthreads();
    #pragma unroll
    for (int i = 0; i < 4; ++i) {
        int n = m0 + ty + 8 * i, k = k0 + tx;
        int nd = n;
        if (interleave) {
            if (n < DII)        nd = ((n >> 4) << 5) + (n & 15);
            else if (n < DI2) { int m = n - DII; nd = ((m >> 4) << 5) + 16 + (m & 15); }
            else              { int q = n - DI2; int j = DII + (q >> 1);
                                nd = ((j >> 4) << 5) + ((q & 1) << 4) + (j & 15); }
        }
        dst[(size_t)nd * Kpad + k] = __float2bfloat16(tile[tx][ty + 8 * i]);
    }
}

// ---------------- RMSNorm: one wave per row, float4 loads, shuffle reduce ----------------
template<int BF16OUT>
__global__ __launch_bounds__(256)
void rms_kernel(const float* __restrict__ x, const float* __restrict__ w,
                void* __restrict__ out, int perm) {
    int wave = threadIdx.x >> 6, lane = threadIdx.x & 63;
    int r = blockIdx.x * 4 + wave;
    int src = r;
    if (perm) {
        int t = r & 15; int rs = r >> 4; int s = rs % SSQ; int b = rs / SSQ;
        src = (b * TT + t) * SSQ + s;
    }
    const float4* xr = (const float4*)(x + (size_t)src * DIMD) + lane * 2;
    float4 a = xr[0], c = xr[1];
    float ss = a.x*a.x + a.y*a.y + a.z*a.z + a.w*a.w
             + c.x*c.x + c.y*c.y + c.z*c.z + c.w*c.w;
    ss += __shfl_xor(ss, 1);  ss += __shfl_xor(ss, 2);  ss += __shfl_xor(ss, 4);
    ss += __shfl_xor(ss, 8);  ss += __shfl_xor(ss, 16); ss += __shfl_xor(ss, 32);
    float sc = rsqrtf(ss * (1.f / DIMD) + EPSR);
    const float4* wr = (const float4*)w + lane * 2;
    float4 wa = wr[0], wb = wr[1];
    if (BF16OUT) {
        short8 v;
        v[0] = f2bfs(a.x * sc * wa.x); v[1] = f2bfs(a.y * sc * wa.y);
        v[2] = f2bfs(a.z * sc * wa.z); v[3] = f2bfs(a.w * sc * wa.w);
        v[4] = f2bfs(c.x * sc * wb.x); v[5] = f2bfs(c.y * sc * wb.y);
        v[6] = f2bfs(c.z * sc * wb.z); v[7] = f2bfs(c.w * sc * wb.w);
        *(short8*)((bf16*)out + (size_t)r * DIMD + lane * 8) = v;
    } else {
        float4* o = (float4*)((float*)out + (size_t)r * DIMD) + lane * 2;
        float4 o0 = {a.x * sc * wa.x, a.y * sc * wa.y, a.z * sc * wa.z, a.w * sc * wa.w};
        float4 o1 = {c.x * sc * wb.x, c.y * sc * wb.y, c.z * sc * wb.z, c.w * sc * wb.w};
        o[0] = o0; o[1] = o1;
    }
}

// ---------------- big MFMA GEMM: 256x256 tile, 8 waves, BK=64 ----------------
// Per-wave output 128x64 (2m x 4n wave grid), 64 MFMA per wave per K-iter:
// amortizes the per-iter barrier over 4x more matrix work than the 128 tile
// and brings LDS-read bytes/MFMA under the 85 B/cy LDS ceiling. 128KB LDS,
// 1 block/CU (2 waves/SIMD) -- latency hidden by per-iter compute depth,
// not TLP. Granule swizzle c = kc ^ (m&7) (same proven conflict-free family).
// EPI: 1 = qkv + fused l2norm/gamma/rotary; 2 = glu (block-16 interleave).
template<int EPI>
__global__ __launch_bounds__(512, 2)
void mfma_gemm_big(const bf16* __restrict__ A, int lda,
                   const bf16* __restrict__ Bt, int ldb,
                   const float* __restrict__ bias,
                   void* __restrict__ C, int ldc,
                   int nrow, int K,
                   const float* __restrict__ qg, const float* __restrict__ kg,
                   int rotary) {
    __shared__ __align__(16) short lds_a[2][256 * 64];
    __shared__ __align__(16) short lds_b[2][256 * 64];
    int tid = threadIdx.x;
    int wave = tid >> 6, lane = tid & 63;
    int quad = lane >> 4, l16 = lane & 15;
    int m0 = blockIdx.y * 256, n0 = blockIdx.x * 256;
    int wm = (wave >> 2) * 128, wn = (wave & 3) * 64;
    f32x4 zero4 = {0.f, 0.f, 0.f, 0.f};
    f32x4 acc[8][4];
    #pragma unroll
    for (int i = 0; i < 8; ++i)
        #pragma unroll
        for (int j = 0; j < 4; ++j) acc[i][j] = zero4;

    const short* Ap = (const short*)A;
    const short* Bp = (const short*)Bt;
    // staging: 2048 granules of 16B per operand; granule g=(m<<3)|kc holds
    // global chunk kc^(m&7) of row m. 4 A + 4 B async16 per thread.
    const short* gA[4]; const short* gB[4];
    #pragma unroll
    for (int j = 0; j < 4; ++j) {
        int g = (wave * 4 + j) * 64 + lane;
        int m = g >> 3, kc = g & 7;
        int csrc = kc ^ (m & 7);
        int r = m0 + m; if (r >= nrow) r = nrow - 1;
        gA[j] = Ap + (size_t)r * lda + csrc * 8;
        gB[j] = Bp + (size_t)(n0 + m) * ldb + csrc * 8;
    }

    auto stage = [&](int buf, int kt) {
        int ko = kt * 64;
        #pragma unroll
        for (int j = 0; j < 4; ++j)
            async16(gA[j] + ko, &lds_a[buf][(wave * 4 + j) * 512]);
        #pragma unroll
        for (int j = 0; j < 4; ++j)
            async16(gB[j] + ko, &lds_b[buf][(wave * 4 + j) * 512]);
    };

    int nk = K >> 6;
    stage(0, 0);
    for (int kt = 0; kt < nk; ++kt) {
        int buf = kt & 1;
        __syncthreads();                       // stage(kt) complete
        if (kt + 1 < nk) stage(buf ^ 1, kt + 1);
        #pragma unroll
        for (int ks = 0; ks < 2; ++ks) {
            short8 af[8], bfr[4];
            #pragma unroll
            for (int mi = 0; mi < 8; ++mi) {
                int m = wm + mi * 16 + l16;
                int c = (ks * 4 + quad) ^ (m & 7);
                af[mi] = *(const short8*)&lds_a[buf][(m * 8 + c) * 8];
            }
            #pragma unroll
            for (int nj = 0; nj < 4; ++nj) {
                int n = wn + nj * 16 + l16;
                int c = (ks * 4 + quad) ^ (n & 7);
                bfr[nj] = *(const short8*)&lds_b[buf][(n * 8 + c) * 8];
            }
            #pragma unroll
            for (int mi = 0; mi < 8; ++mi)
                #pragma unroll
                for (int nj = 0; nj < 4; ++nj)
                    acc[mi][nj] = __builtin_amdgcn_mfma_f32_16x16x32_bf16(
                        af[mi], bfr[nj], acc[mi][nj], 0, 0, 0);
        }
    }

    if constexpr (EPI == 1) {
        // qkv: wave covers exactly one 64-col head.
        int head = (n0 + wn) >> 6;          // 0..15 q, 16..23 k, 24..31 v
        float gl0 = 0.f, gl1 = 0.f, gl2 = 0.f, gl3 = 0.f, inv0 = 0.f, inv1 = 0.f;
        if (head < 24) {
            const float* g = head < 16 ? qg + head * 64 : kg + (head - 16) * 64;
            gl0 = (g[l16] + 1.f) * 8.f;
            gl1 = (g[16 + l16] + 1.f) * 8.f;
            gl2 = (g[32 + l16] + 1.f) * 8.f;
            gl3 = (g[48 + l16] + 1.f) * 8.f;
            if (rotary) {
                inv0 = __expf(-(float)l16 * 0.28782313662425572f);        // ln(1e4)/32
                inv1 = __expf(-(float)(l16 + 16) * 0.28782313662425572f);
            }
        }
        #pragma unroll
        for (int mi = 0; mi < 8; ++mi) {
            #pragma unroll
            for (int e = 0; e < 4; ++e) {
                int row = m0 + wm + mi * 16 + quad * 4 + e;
                float v0 = acc[mi][0][e], v1 = acc[mi][1][e];
                float v2 = acc[mi][2][e], v3 = acc[mi][3][e];
                if (head < 24) {
                    float ss = v0 * v0 + v1 * v1 + v2 * v2 + v3 * v3;
                    ss += __shfl_xor(ss, 1); ss += __shfl_xor(ss, 2);
                    ss += __shfl_xor(ss, 4); ss += __shfl_xor(ss, 8);
                    float invn = 1.f / fmaxf(sqrtf(ss), 1e-12f);
                    v0 *= invn * gl0; v1 *= invn * gl1;
                    v2 *= invn * gl2; v3 *= invn * gl3;
                    if (rotary) {
                        float t = (float)(row & 15);
                        float a0 = t * inv0, a1 = t * inv1;
                        float c0 = __cosf(a0), s0 = __sinf(a0);
                        float c1 = __cosf(a1), s1 = __sinf(a1);
                        float n0v = v0 * c0 - v2 * s0;
                        float n1v = v1 * c1 - v3 * s1;
                        float n2v = v2 * c0 + v0 * s0;
                        float n3v = v3 * c1 + v1 * s1;
                        v0 = n0v; v1 = n1v; v2 = n2v; v3 = n3v;
                    }
                }
                if (row < nrow) {
                    bf16* p = (bf16*)C + (size_t)row * ldc + n0 + wn + l16;
                    p[0]  = __float2bfloat16(v0);
                    p[16] = __float2bfloat16(v1);
                    p[32] = __float2bfloat16(v2);
                    p[48] = __float2bfloat16(v3);
                }
            }
        }
    } else {
        // block-16 interleave: nj 0/2 = a, nj 1/3 = g for same j in SAME lane.
        int jbase = (n0 + wn) >> 1;
        int j0 = jbase + l16, j1 = jbase + 16 + l16;
        float ba0 = (j0 < DII) ? bias[j0] : 0.f;
        float bg0 = (j0 < DII) ? bias[DII + j0] : 0.f;
        float ba1 = (j1 < DII) ? bias[j1] : 0.f;
        float bg1 = (j1 < DII) ? bias[DII + j1] : 0.f;
        #pragma unroll
        for (int mi = 0; mi < 8; ++mi) {
            #pragma unroll
            for (int e = 0; e < 4; ++e) {
                int row = m0 + wm + mi * 16 + quad * 4 + e;
                if (row < nrow) {
                    bf16* cr = (bf16*)C + (size_t)row * ldc;
                    cr[j0] = __float2bfloat16(
                        glu_fast(acc[mi][0][e] + ba0, acc[mi][1][e] + bg0));
                    cr[j1] = __float2bfloat16(
                        glu_fast(acc[mi][2][e] + ba1, acc[mi][3][e] + bg1));
                }
            }
        }
    }
}

// ---------------- MFMA bf16 GEMM (small): C[nrow,M] = A @ Bt^T ----------------
// TM x 128 tile, BK=32, double-buffered, granule swizzle kc' = kc^((m>>1)&3).
// 4 waves. EPI 3 = fp32 accumulate (+= into C), optional PERM store.
template<int EPI, int PERM, int TM>
__global__ __launch_bounds__(256)
void mfma_gemm(const bf16* __restrict__ A, int lda,
               const bf16* __restrict__ Bt, int ldb,
               const float* __restrict__ bias,
               void* __restrict__ C, int ldc, int Mstore,
               int nrow, int K) {
    constexpr int MI = TM / 32;
    constexpr int ALW = TM / 64;
    __shared__ __align__(16) short lds_a[2][TM * 32];
    __shared__ __align__(16) short lds_b[2][128 * 32];
    int tid = threadIdx.x;
    int wave = tid >> 6, lane = tid & 63;
    int quad = lane >> 4, l16 = lane & 15;
    int m0 = blockIdx.y * TM, n0 = blockIdx.x * 128;
    int wm = (wave & 1) * (TM / 2), wn = (wave >> 1) * 64;
    f32x4 zero4 = {0.f, 0.f, 0.f, 0.f};
    f32x4 acc[MI][4];
    #pragma unroll
    for (int i = 0; i < MI; ++i)
        #pragma unroll
        for (int j = 0; j < 4; ++j) acc[i][j] = zero4;

    const short* Ap = (const short*)A;
    const short* Bp = (const short*)Bt;
    auto aptr = [&](int g) {
        int m = g >> 2, kc = (g & 3) ^ ((g >> 3) & 3);
        int r = m0 + m; if (r >= nrow) r = nrow - 1;
        return Ap + (size_t)r * lda + kc * 8;
    };
    auto bptr = [&](int g) {
        int m = g >> 2, kc = (g & 3) ^ ((g >> 3) & 3);
        return Bp + (size_t)(n0 + m) * ldb + kc * 8;
    };
    const short* gA[ALW]; int aoff[ALW];
    #pragma unroll
    for (int j = 0; j < ALW; ++j) {
        gA[j] = aptr(wave * TM + j * 64 + lane);
        aoff[j] = (wave * TM + j * 64) * 8;
    }
    const short* gB0 = bptr(wave * 128 + lane);
    const short* gB1 = bptr(wave * 128 + 64 + lane);
    int boff0 = (wave * 128) * 8, boff1 = (wave * 128 + 64) * 8;

    auto stage = [&](int buf, int kt) {
        int ko = kt * 32;
        #pragma unroll
        for (int j = 0; j < ALW; ++j)
            async16(gA[j] + ko, &lds_a[buf][aoff[j]]);
        async16(gB0 + ko, &lds_b[buf][boff0]);
        async16(gB1 + ko, &lds_b[buf][boff1]);
    };

    int nk = K >> 5;
    stage(0, 0);
    for (int kt = 0; kt < nk; ++kt) {
        int buf = kt & 1;
        __syncthreads();
        if (kt + 1 < nk) stage(buf ^ 1, kt + 1);
        short8 af[MI], bfr[4];
        #pragma unroll
        for (int mi = 0; mi < MI; ++mi) {
            int m = wm + mi * 16 + l16;
            af[mi] = *(const short8*)&lds_a[buf][(m * 4 + (quad ^ ((m >> 1) & 3))) * 8];
        }
        #pragma unroll
        for (int nj = 0; nj < 4; ++nj) {
            int n = wn + nj * 16 + l16;
            bfr[nj] = *(const short8*)&lds_b[buf][(n * 4 + (quad ^ ((n >> 1) & 3))) * 8];
        }
        #pragma unroll
        for (int mi = 0; mi < MI; ++mi)
            #pragma unroll
            for (int nj = 0; nj < 4; ++nj)
                acc[mi][nj] = __builtin_amdgcn_mfma_f32_16x16x32_bf16(
                    af[mi], bfr[nj], acc[mi][nj], 0, 0, 0);
    }

    #pragma unroll
    for (int mi = 0; mi < MI; ++mi) {
        #pragma unroll
        for (int e = 0; e < 4; ++e) {
            int row = m0 + wm + mi * 16 + quad * 4 + e;
            if (row >= nrow) continue;
            int orow = row;
            if (PERM) {
                int t = row & 15; int rs = row >> 4; int s = rs % SSQ; int b = rs / SSQ;
                orow = (b * TT + t) * SSQ + s;
            }
            #pragma unroll
            for (int nj = 0; nj < 4; ++nj) {
                int col = n0 + wn + nj * 16 + l16;
                if (col >= Mstore) continue;
                float v = acc[mi][nj][e];
                if (bias) v += bias[col];
                ((float*)C)[(size_t)orow * ldc + col] += v;
            }
        }
    }
}

// ---------------- V transpose for PV MFMA: vt[bt*8+kh][64][SKP] bf16 ----------------
__global__ void vtrans_kernel(const bf16* __restrict__ qkv, bf16* __restrict__ vt) {
    int bkh = blockIdx.x;          // bt*8 + kh
    int kc = blockIdx.y;           // key chunk of 32
    int bt = bkh >> 3, kh = bkh & 7;
    int tid = threadIdx.x;
    #pragma unroll
    for (int i = 0; i < 8; ++i) {
        int idx = tid + 256 * i;   // 0..2047
        int kl = idx >> 6;         // key local
        int d = idx & 63;
        int key = kc * 32 + kl;
        float v = 0.f;
        if (key < SSQ)
            v = __bfloat162float(qkv[((size_t)(bt * SSQ + key)) * 2048 + 1536 + kh * 64 + d]);
        vt[((size_t)bkh * 64 + d) * SKP + key] = __float2bfloat16(v);
    }
}

// ---------------- space attention: S^T in registers, K staged in LDS ----------------
__global__ __launch_bounds__(256)
void space_attn_kernel(const bf16* __restrict__ qkv, const bf16* __restrict__ vt,
                       bf16* __restrict__ ob) {
    __shared__ __align__(16) short kls[272 * 8 * 8];   // granule (key,c): K[key][8*(c^(key&7))..+8)
    int qt = blockIdx.x, qh = blockIdx.y, bt = blockIdx.z;
    int kh = qh >> 1;
    int tid = threadIdx.x, wave = tid >> 6, lane = tid & 63;
    int quad = lane >> 4, l16 = lane & 15;
    int q0w = qt * 64 + wave * 16;
    int q = q0w + l16;
    int qc = q > 256 ? 256 : q;
    const short* qbase = (const short*)qkv + (size_t)bt * SSQ * 2048;

    const short* kgbase = qbase + 1024 + kh * 64;
    #pragma unroll
    for (int it = 0; it < 9; ++it) {
        int u = it * 4 + wave;
        if (u < 34) {
            int g = u * 64 + lane;
            int key = g >> 3, ch = g & 7;
            int srck = key < SSQ ? key : 256;
            async16(kgbase + (size_t)srck * 2048 + (ch ^ (key & 7)) * 8,
                    &kls[u * 512]);
        }
    }

    const short* qp = qbase + (size_t)qc * 2048 + qh * 64;
    short8 bq0 = *(const short8*)(qp + quad * 8);
    short8 bq1 = *(const short8*)(qp + 32 + quad * 8);
    __syncthreads();   // drains vmcnt: K staged

    f32x4 zero4 = {0.f, 0.f, 0.f, 0.f};
    f32x4 sc[18];
    float sum = 0.f;
    int c0 = quad ^ (l16 & 7);   // key&7 == l16&7 since kt*16 % 8 == 0
    #pragma unroll
    for (int kt = 0; kt < 17; ++kt) {
        int key = kt * 16 + l16;
        short8 ak0 = *(const short8*)&kls[(key * 8 + c0) * 8];
        short8 ak1 = *(const short8*)&kls[(key * 8 + (c0 ^ 4)) * 8];
        f32x4 cc = zero4;
        cc = __builtin_amdgcn_mfma_f32_16x16x32_bf16(ak0, bq0, cc, 0, 0, 0);
        cc = __builtin_amdgcn_mfma_f32_16x16x32_bf16(ak1, bq1, cc, 0, 0, 0);
        #pragma unroll
        for (int e = 0; e < 4; ++e) {
            float x = cc[e] * 0.0025f;           // s/50, s = dot/8
            float x2 = x * x;
            float v = cc[e] * 0.125f * (1.f + x2 * (-0.3333333333f + x2 * 0.1333333333f));
            float p = __expf(v);                 // v in [-8.1, 8.1]: no overflow
            if (kt == 16) {
                bool valid = (e == 0) && (quad == 0) && (q == 256);
                p = valid ? p : 0.f;
            }
            cc[e] = p;
            sum += p;
        }
        sc[kt] = cc;
    }
    #pragma unroll
    for (int e = 0; e < 4; ++e) sc[17][e] = 0.f;
    sum += __shfl_xor(sum, 16);
    sum += __shfl_xor(sum, 32);
    float inv = __builtin_amdgcn_rcpf(sum);
    f32x4 inv4;
    #pragma unroll
    for (int e = 0; e < 4; ++e) inv4[e] = __shfl(inv, quad * 4 + e);

    f32x4 oacc[4];
    #pragma unroll
    for (int nt = 0; nt < 4; ++nt) oacc[nt] = zero4;
    const short* vbp = (const short*)vt + ((size_t)(bt * 8 + kh) * 64 + l16) * SKP;
    #pragma unroll
    for (int c8 = 0; c8 < 9; ++c8) {
        short8 pb;
        #pragma unroll
        for (int j = 0; j < 8; ++j) {
            int src_lane = ((quad & 1) * 2 + (j >> 2)) * 16 + l16;
            float v0 = __shfl(sc[2 * c8][j & 3], src_lane);
            float v1 = __shfl(sc[2 * c8 + 1][j & 3], src_lane);
            pb[j] = f2bfs(quad < 2 ? v0 : v1);
        }
        #pragma unroll
        for (int nt = 0; nt < 4; ++nt) {
            short8 av = *(const short8*)(vbp + (size_t)(nt * 16) * SKP + c8 * 32 + quad * 8);
            oacc[nt] = __builtin_amdgcn_mfma_f32_16x16x32_bf16(pb, av, oacc[nt], 0, 0, 0);
        }
    }

    #pragma unroll
    for (int e = 0; e < 4; ++e) {
        int qq = q0w + quad * 4 + e;
        if (qq <= 256) {
            bf16* op = ob + ((size_t)(bt * SSQ + qq)) * 1024 + qh * 64 + l16;
            float s = inv4[e];
            op[0]  = __float2bfloat16(oacc[0][e] * s);
            op[16] = __float2bfloat16(oacc[1][e] * s);
            op[32] = __float2bfloat16(oacc[2][e] * s);
            op[48] = __float2bfloat16(oacc[3][e] * s);
        }
    }
}

// ---------------- time attention (n=16, causal): one block per (b*s, qh) ----------------
__global__ void time_attn_kernel(const bf16* __restrict__ qkv, bf16* __restrict__ ob) {
    __shared__ float qs[16][65], ks[16][65], ps[16][17];
    int bs = blockIdx.x, qh = blockIdx.y, kh = qh >> 1;
    int tid = threadIdx.x;
    size_t rowbase = (size_t)bs * 16;
    #pragma unroll
    for (int i = 0; i < 4; ++i) {
        int idx = tid + 256 * i;
        int r = idx >> 6, d = idx & 63;
        qs[r][d] = __bfloat162float(qkv[(rowbase + r) * 2048 + qh * 64 + d]);
        ks[r][d] = __bfloat162float(qkv[(rowbase + r) * 2048 + 1024 + kh * 64 + d]);
    }
    __syncthreads();
    int i = tid >> 4, j = tid & 15;
    float dot = 0.f;
    #pragma unroll 16
    for (int d = 0; d < 64; ++d) dot += qs[i][d] * ks[j][d];
    float s = dot * 0.125f;
    float x = s * 0.02f;
    float x2 = x * x;
    float v = s * (1.f + x2 * (-0.3333333333f + x2 * 0.1333333333f));
    float p = (j > i) ? 0.f : __expf(v);
    float sum = p;
    sum += __shfl_xor(sum, 1);
    sum += __shfl_xor(sum, 2);
    sum += __shfl_xor(sum, 4);
    sum += __shfl_xor(sum, 8);
    ps[i][j] = p * __builtin_amdgcn_rcpf(sum);
    __syncthreads();
    #pragma unroll
    for (int ii = 0; ii < 4; ++ii) {
        int idx = tid + 256 * ii;
        int r = idx >> 6, d = idx & 63;
        float acc = 0.f;
        #pragma unroll
        for (int jj = 0; jj < 16; ++jj)
            acc += ps[r][jj] * __bfloat162float(qkv[(rowbase + jj) * 2048 + 1536 + kh * 64 + d]);
        ob[(rowbase + r) * 1024 + qh * 64 + d] = __float2bfloat16(acc);
    }
}

// ---------------- host-side launch ----------------
extern "C" void kernel_launch(void* const* d_in, const int* in_sizes, int n_in,
                              void* d_out, int out_size, void* d_ws, size_t ws_size,
                              hipStream_t stream) {
    const float* tokens      = (const float*)d_in[0];
    const float* attn_norm_w = (const float*)d_in[1];
    const float* Wq          = (const float*)d_in[2];
    const float* Wk          = (const float*)d_in[3];
    const float* Wv          = (const float*)d_in[4];
    const float* q_gamma     = (const float*)d_in[5];
    const float* k_gamma     = (const float*)d_in[6];
    const float* Wo          = (const float*)d_in[7];
    const float* ff_norm_w   = (const float*)d_in[8];
    const float* W_in        = (const float*)d_in[9];
    const float* b_in        = (const float*)d_in[10];
    const float* W_out       = (const float*)d_in[11];
    const float* b_out       = (const float*)d_in[12];
    const float* final_w     = (const float*)d_in[13];

    float* x = (float*)d_out;
    char* ws = (char*)d_ws;

    bf16* wtqkv = (bf16*)ws;                     // [2048][512]
    bf16* wto   = wtqkv + 2048 * 512;            // [512][1024]
    bf16* wtin  = wto   + 512 * 1024;            // [2816][512] interleaved
    bf16* wtout = wtin  + 2816 * 512;            // [512][1408]
    size_t off = (size_t)(2048*512 + 512*1024 + 2816*512 + 512*1408) * 2;
    bf16* h = (bf16*)(ws + off);                 // [N][512]
    off += (size_t)NROWS * 512 * 2;
    char* region = ws + off;
    bf16* qkv = (bf16*)region;                               // [N][2048]
    bf16* glu = (bf16*)region;                               // [N][1408] (FF alias)
    bf16* vt  = (bf16*)(region + (size_t)NROWS * 2048 * 2);  // [256][64][288]
    bf16* ob  = (bf16*)(region + (size_t)NROWS * 2048 * 2 + (size_t)256*64*SKP*2);  // [N][1024]

    hipMemcpyAsync(x, tokens, (size_t)NROWS * 512 * 4, hipMemcpyDeviceToDevice, stream);

    for (int l = 0; l < 8; ++l) {
        int is_time = ((l + 1) % 4 == 0) ? 1 : 0;
        wtrans_layer<<<3648, 256, 0, stream>>>(
            Wq + (size_t)l * 512 * 1024, Wk + (size_t)l * 512 * 512,
            Wv + (size_t)l * 512 * 512, Wo + (size_t)l * 1024 * 512,
            W_in + (size_t)l * 512 * DI2, W_out + (size_t)l * DII * 512,
            wtqkv, wto, wtin, wtout);

        // ---- attention block ----
        rms_kernel<1><<<2056, 256, 0, stream>>>(x, attn_norm_w + (size_t)l * 512, h, is_time);
        mfma_gemm_big<1><<<dim3(8, 33), 512, 0, stream>>>(
            h, 512, wtqkv, 512, nullptr, qkv, 2048, NROWS, 512,
            q_gamma + (size_t)l * 1024, k_gamma + (size_t)l * 512, is_time);
        if (is_time) {
            time_attn_kernel<<<dim3(514, 16), 256, 0, stream>>>(qkv, ob);
            mfma_gemm<3, 1, 64><<<dim3(4, 129), 256, 0, stream>>>(
                ob, 1024, wto, 1024, nullptr, x, 512, 512, NROWS, 1024);
        } else {
            vtrans_kernel<<<dim3(256, 9), 256, 0, stream>>>(qkv, vt);
            space_attn_kernel<<<dim3(5, 16, 32), 256, 0, stream>>>(qkv, vt, ob);
            mfma_gemm<3, 0, 64><<<dim3(4, 129), 256, 0, stream>>>(
                ob, 1024, wto, 1024, nullptr, x, 512, 512, NROWS, 1024);
        }

        // ---- feed-forward block ----
        rms_kernel<1><<<2056, 256, 0, stream>>>(x, ff_norm_w + (size_t)l * 512, h, 0);
        mfma_gemm_big<2><<<dim3(11, 33), 512, 0, stream>>>(
            h, 512, wtin, 512, b_in + (size_t)l * DI2, glu, GLULD, NROWS, 512,
            nullptr, nullptr, 0);
        mfma_gemm<3, 0, 64><<<dim3(4, 129), 256, 0, stream>>>(
            glu, GLULD, wtout, GLULD, b_out + (size_t)l * 512, x, 512, 512, NROWS, GLULD);
    }

    rms_kernel<0><<<2056, 256, 0, stream>>>(x, final_w, x, 0);
}

// Round 5
// 2302.468 us; speedup vs baseline: 1.1701x; 1.0171x over previous
//
#include <hip/hip_runtime.h>
#include <hip/hip_bf16.h>
#include <math.h>

typedef __attribute__((ext_vector_type(8))) short short8;
typedef __attribute__((ext_vector_type(4))) float f32x4;
typedef __hip_bfloat16 bf16;

#define BB 2
#define TT 16
#define SSQ 257
#define DIMD 512
#define NROWS 8224          // B*T*S
#define DII 1365
#define DI2 2730
#define FNPAD 2816          // ff_in N padded (22*128), block-16 interleaved a/g
#define GLULD 1408          // glu row stride / ff_out K (44*32)
#define SKP 288             // padded key count for space attn
#define EPSR 1.1920929e-07f

__device__ __forceinline__ void async16(const void* g, const void* l) {
    __builtin_amdgcn_global_load_lds(
        (const __attribute__((address_space(1))) void*)g,
        (__attribute__((address_space(3))) void*)l, 16, 0, 0);
}

__device__ __forceinline__ short f2bfs(float x) {
    bf16 h = __float2bfloat16(x);
    return *reinterpret_cast<short*>(&h);
}

// fast exact-gelu: a * g * Phi(g), erf via A&S 7.1.26 (abs err 1.5e-7)
__device__ __forceinline__ float glu_fast(float a, float g) {
    float x = g * 0.70710678118654752f;
    float ax = fabsf(x);
    float t = __builtin_amdgcn_rcpf(__builtin_fmaf(0.3275911f, ax, 1.f));
    float p = t * (0.254829592f + t * (-0.284496736f + t * (1.421413741f
              + t * (-1.453152027f + t * 1.061405429f))));
    float erfv = 1.f - p * __expf(-ax * ax);
    erfv = (x < 0.f) ? -erfv : erfv;
    return a * 0.5f * g * (1.f + erfv);
}

// ---------------- batched per-layer weight transpose fp32->bf16 ----------------
// win interleave: a_j -> col (j>>4)*32 + (j&15); g_j -> col (j>>4)*32 + 16 + (j&15)
__global__ void wtrans_layer(const float* __restrict__ wq, const float* __restrict__ wk,
                             const float* __restrict__ wv, const float* __restrict__ wo,
                             const float* __restrict__ win, const float* __restrict__ wout,
                             bf16* __restrict__ dqkv, bf16* __restrict__ dwo,
                             bf16* __restrict__ dwin, bf16* __restrict__ dwout) {
    __shared__ float tile[32][33];
    int bid = blockIdx.x;
    const float* src; bf16* dst; int K, M, Kpad, interleave = 0, local;
    if (bid < 512)       { src = wq;   dst = dqkv;            K = 512;  M = 1024; Kpad = 512;  local = bid; }
    else if (bid < 768)  { src = wk;   dst = dqkv + 1024*512; K = 512;  M = 512;  Kpad = 512;  local = bid - 512; }
    else if (bid < 1024) { src = wv;   dst = dqkv + 1536*512; K = 512;  M = 512;  Kpad = 512;  local = bid - 768; }
    else if (bid < 1536) { src = wo;   dst = dwo;             K = 1024; M = 512;  Kpad = 1024; local = bid - 1024; }
    else if (bid < 2944) { src = win;  dst = dwin;            K = 512;  M = 2730; Kpad = 512;  local = bid - 1536; interleave = 1; }
    else                 { src = wout; dst = dwout;           K = 1365; M = 512;  Kpad = 1408; local = bid - 2944; }
    int tilesx = Kpad >> 5;
    int k0 = (local % tilesx) * 32, m0 = (local / tilesx) * 32;
    int tx = threadIdx.x & 31, ty = threadIdx.x >> 5;
    #pragma unroll
    for (int i = 0; i < 4; ++i) {
        int k = k0 + ty + 8 * i, m = m0 + tx;
        tile[ty + 8 * i][tx] = (k < K && m < M) ? src[(size_t)k * M + m] : 0.f;
    }
    __syncthreads();
    #pragma unroll
    for (int i = 0; i < 4; ++i) {
        int n = m0 + ty + 8 * i, k = k0 + tx;
        int nd = n;
        if (interleave) {
            if (n < DII)        nd = ((n >> 4) << 5) + (n & 15);
            else if (n < DI2) { int m = n - DII; nd = ((m >> 4) << 5) + 16 + (m & 15); }
            else              { int q = n - DI2; int j = DII + (q >> 1);
                                nd = ((j >> 4) << 5) + ((q & 1) << 4) + (j & 15); }
        }
        dst[(size_t)nd * Kpad + k] = __float2bfloat16(tile[tx][ty + 8 * i]);
    }
}

// ---------------- RMSNorm: one wave per row, float4 loads, shuffle reduce ----------------
template<int BF16OUT>
__global__ __launch_bounds__(256)
void rms_kernel(const float* __restrict__ x, const float* __restrict__ w,
                void* __restrict__ out, int perm) {
    int wave = threadIdx.x >> 6, lane = threadIdx.x & 63;
    int r = blockIdx.x * 4 + wave;
    int src = r;
    if (perm) {
        int t = r & 15; int rs = r >> 4; int s = rs % SSQ; int b = rs / SSQ;
        src = (b * TT + t) * SSQ + s;
    }
    const float4* xr = (const float4*)(x + (size_t)src * DIMD) + lane * 2;
    float4 a = xr[0], c = xr[1];
    float ss = a.x*a.x + a.y*a.y + a.z*a.z + a.w*a.w
             + c.x*c.x + c.y*c.y + c.z*c.z + c.w*c.w;
    ss += __shfl_xor(ss, 1);  ss += __shfl_xor(ss, 2);  ss += __shfl_xor(ss, 4);
    ss += __shfl_xor(ss, 8);  ss += __shfl_xor(ss, 16); ss += __shfl_xor(ss, 32);
    float sc = rsqrtf(ss * (1.f / DIMD) + EPSR);
    const float4* wr = (const float4*)w + lane * 2;
    float4 wa = wr[0], wb = wr[1];
    if (BF16OUT) {
        short8 v;
        v[0] = f2bfs(a.x * sc * wa.x); v[1] = f2bfs(a.y * sc * wa.y);
        v[2] = f2bfs(a.z * sc * wa.z); v[3] = f2bfs(a.w * sc * wa.w);
        v[4] = f2bfs(c.x * sc * wb.x); v[5] = f2bfs(c.y * sc * wb.y);
        v[6] = f2bfs(c.z * sc * wb.z); v[7] = f2bfs(c.w * sc * wb.w);
        *(short8*)((bf16*)out + (size_t)r * DIMD + lane * 8) = v;
    } else {
        float4* o = (float4*)((float*)out + (size_t)r * DIMD) + lane * 2;
        float4 o0 = {a.x * sc * wa.x, a.y * sc * wa.y, a.z * sc * wa.z, a.w * sc * wa.w};
        float4 o1 = {c.x * sc * wb.x, c.y * sc * wb.y, c.z * sc * wb.z, c.w * sc * wb.w};
        o[0] = o0; o[1] = o1;
    }
}

// ---------------- big MFMA GEMM: 256x256 tile, 8 waves, 8-phase schedule ----------------
// Port of the proven 8-phase template (same phase density: per 64-K, 4 phases of
// {ds_read quarter + 2 staging loads + barrier + setprio'd 16 MFMA + barrier}).
// BK=32 steps, FOUR LDS step-buffers (128 KB), counted vmcnt ledger:
//   prologue stages steps 0..2 (12 loads/thread in flight);
//   step s entry: vmcnt(8) drains exactly step s's 4 loads; barrier;
//   during step s, phases stage step s+3 into buf (s-1)&3 (reads of that
//   buffer finished before this step's entry barrier -> no race);
//   tail: vmcnt 8 -> 4 -> 0. T1 bijective XCD swizzle on linear block id.
// EPI: 1 = qkv + fused l2norm/gamma/rotary; 2 = glu (block-16 interleave).
template<int EPI>
__global__ __launch_bounds__(512, 2)
void mfma_gemm_big(const bf16* __restrict__ A, int lda,
                   const bf16* __restrict__ Bt, int ldb,
                   const float* __restrict__ bias,
                   void* __restrict__ C, int ldc,
                   int nrow, int K,
                   const float* __restrict__ qg, const float* __restrict__ kg,
                   int rotary) {
    __shared__ __align__(16) short lds_a[4][256 * 32];
    __shared__ __align__(16) short lds_b[4][256 * 32];
    // T1: bijective XCD-aware remap (m204) of the linear block id
    int nwg = gridDim.x * gridDim.y;
    int lin = blockIdx.y * gridDim.x + blockIdx.x;
    int q8 = nwg >> 3, r8 = nwg & 7;
    int xcd = lin & 7, idx = lin >> 3;
    int w = (xcd < r8 ? xcd * (q8 + 1) : r8 * (q8 + 1) + (xcd - r8) * q8) + idx;
    int bx = w % gridDim.x, by = w / gridDim.x;
    int m0 = by * 256, n0 = bx * 256;

    int tid = threadIdx.x;
    int wave = tid >> 6, lane = tid & 63;
    int quad = lane >> 4, l16 = lane & 15;
    int wm = (wave >> 2) * 128, wn = (wave & 3) * 64;
    f32x4 zero4 = {0.f, 0.f, 0.f, 0.f};
    f32x4 acc[8][4];
    #pragma unroll
    for (int i = 0; i < 8; ++i)
        #pragma unroll
        for (int j = 0; j < 4; ++j) acc[i][j] = zero4;

    const short* Ap = (const short*)A;
    const short* Bp = (const short*)Bt;
    // staging: 1024 granules of 16B per operand per step; granule g=(m<<2)|kc
    // holds global chunk kc^((m>>1)&3) of row m. 2 A + 2 B async16 per thread.
    const short* gA[2]; const short* gB[2]; int goff[2];
    #pragma unroll
    for (int j = 0; j < 2; ++j) {
        int g = wave * 128 + j * 64 + lane;
        int m = g >> 2, kc = g & 3;
        int csrc = kc ^ ((m >> 1) & 3);
        int r = m0 + m; if (r >= nrow) r = nrow - 1;
        gA[j] = Ap + (size_t)r * lda + csrc * 8;
        gB[j] = Bp + (size_t)(n0 + m) * ldb + csrc * 8;
        goff[j] = g * 8;
    }

    int nk = K >> 5;                 // 16 for K=512
    // prologue: stage steps 0,1,2
    #pragma unroll
    for (int s = 0; s < 3; ++s) {
        async16(gA[0] + s * 32, &lds_a[s][goff[0]]);
        async16(gB[0] + s * 32, &lds_b[s][goff[0]]);
        async16(gA[1] + s * 32, &lds_a[s][goff[1]]);
        async16(gB[1] + s * 32, &lds_b[s][goff[1]]);
    }

    for (int s = 0; s < nk; ++s) {
        int buf = s & 3;
        int rem = nk - 1 - s;
        if (rem >= 2)      asm volatile("s_waitcnt vmcnt(8)" ::: "memory");
        else if (rem == 1) asm volatile("s_waitcnt vmcnt(4)" ::: "memory");
        else               asm volatile("s_waitcnt vmcnt(0)" ::: "memory");
        __builtin_amdgcn_s_barrier();
        __builtin_amdgcn_sched_barrier(0);
        bool st = (s + 3 < nk);
        int sb = (s + 3) & 3;
        int ko = (s + 3) * 32;
        const short* la = lds_a[buf];
        const short* lb = lds_b[buf];
        short8 af[8], bfr[4];
        // ---- phase 1: read mi0-3 + all bf, stage 2, 16 MFMA
        #pragma unroll
        for (int mi = 0; mi < 4; ++mi) {
            int m = wm + mi * 16 + l16;
            af[mi] = *(const short8*)&la[(m * 4 + (quad ^ ((m >> 1) & 3))) * 8];
        }
        #pragma unroll
        for (int nj = 0; nj < 4; ++nj) {
            int n = wn + nj * 16 + l16;
            bfr[nj] = *(const short8*)&lb[(n * 4 + (quad ^ ((n >> 1) & 3))) * 8];
        }
        if (st) {
            async16(gA[0] + ko, &lds_a[sb][goff[0]]);
            async16(gB[0] + ko, &lds_b[sb][goff[0]]);
        }
        __builtin_amdgcn_s_barrier();
        __builtin_amdgcn_sched_barrier(0);
        __builtin_amdgcn_s_setprio(1);
        #pragma unroll
        for (int mi = 0; mi < 4; ++mi)
            #pragma unroll
            for (int nj = 0; nj < 4; ++nj)
                acc[mi][nj] = __builtin_amdgcn_mfma_f32_16x16x32_bf16(
                    af[mi], bfr[nj], acc[mi][nj], 0, 0, 0);
        __builtin_amdgcn_s_setprio(0);
        __builtin_amdgcn_s_barrier();
        // ---- phase 2: read mi4-7, stage 2, 16 MFMA
        #pragma unroll
        for (int mi = 4; mi < 8; ++mi) {
            int m = wm + mi * 16 + l16;
            af[mi] = *(const short8*)&la[(m * 4 + (quad ^ ((m >> 1) & 3))) * 8];
        }
        if (st) {
            async16(gA[1] + ko, &lds_a[sb][goff[1]]);
            async16(gB[1] + ko, &lds_b[sb][goff[1]]);
        }
        __builtin_amdgcn_s_barrier();
        __builtin_amdgcn_sched_barrier(0);
        __builtin_amdgcn_s_setprio(1);
        #pragma unroll
        for (int mi = 4; mi < 8; ++mi)
            #pragma unroll
            for (int nj = 0; nj < 4; ++nj)
                acc[mi][nj] = __builtin_amdgcn_mfma_f32_16x16x32_bf16(
                    af[mi], bfr[nj], acc[mi][nj], 0, 0, 0);
        __builtin_amdgcn_s_setprio(0);
        // next step's entry vmcnt+barrier orders everything else
    }

    if constexpr (EPI == 1) {
        // qkv: wave covers exactly one 64-col head.
        int head = (n0 + wn) >> 6;          // 0..15 q, 16..23 k, 24..31 v
        float gl0 = 0.f, gl1 = 0.f, gl2 = 0.f, gl3 = 0.f, inv0 = 0.f, inv1 = 0.f;
        if (head < 24) {
            const float* g = head < 16 ? qg + head * 64 : kg + (head - 16) * 64;
            gl0 = (g[l16] + 1.f) * 8.f;
            gl1 = (g[16 + l16] + 1.f) * 8.f;
            gl2 = (g[32 + l16] + 1.f) * 8.f;
            gl3 = (g[48 + l16] + 1.f) * 8.f;
            if (rotary) {
                inv0 = __expf(-(float)l16 * 0.28782313662425572f);        // ln(1e4)/32
                inv1 = __expf(-(float)(l16 + 16) * 0.28782313662425572f);
            }
        }
        #pragma unroll
        for (int mi = 0; mi < 8; ++mi) {
            #pragma unroll
            for (int e = 0; e < 4; ++e) {
                int row = m0 + wm + mi * 16 + quad * 4 + e;
                float v0 = acc[mi][0][e], v1 = acc[mi][1][e];
                float v2 = acc[mi][2][e], v3 = acc[mi][3][e];
                if (head < 24) {
                    float ss = v0 * v0 + v1 * v1 + v2 * v2 + v3 * v3;
                    ss += __shfl_xor(ss, 1); ss += __shfl_xor(ss, 2);
                    ss += __shfl_xor(ss, 4); ss += __shfl_xor(ss, 8);
                    float invn = 1.f / fmaxf(sqrtf(ss), 1e-12f);
                    v0 *= invn * gl0; v1 *= invn * gl1;
                    v2 *= invn * gl2; v3 *= invn * gl3;
                    if (rotary) {
                        float t = (float)(row & 15);
                        float a0 = t * inv0, a1 = t * inv1;
                        float c0 = __cosf(a0), s0 = __sinf(a0);
                        float c1 = __cosf(a1), s1 = __sinf(a1);
                        float n0v = v0 * c0 - v2 * s0;
                        float n1v = v1 * c1 - v3 * s1;
                        float n2v = v2 * c0 + v0 * s0;
                        float n3v = v3 * c1 + v1 * s1;
                        v0 = n0v; v1 = n1v; v2 = n2v; v3 = n3v;
                    }
                }
                if (row < nrow) {
                    bf16* p = (bf16*)C + (size_t)row * ldc + n0 + wn + l16;
                    p[0]  = __float2bfloat16(v0);
                    p[16] = __float2bfloat16(v1);
                    p[32] = __float2bfloat16(v2);
                    p[48] = __float2bfloat16(v3);
                }
            }
        }
    } else {
        // block-16 interleave: nj 0/2 = a, nj 1/3 = g for same j in SAME lane.
        int jbase = (n0 + wn) >> 1;
        int j0 = jbase + l16, j1 = jbase + 16 + l16;
        float ba0 = (j0 < DII) ? bias[j0] : 0.f;
        float bg0 = (j0 < DII) ? bias[DII + j0] : 0.f;
        float ba1 = (j1 < DII) ? bias[j1] : 0.f;
        float bg1 = (j1 < DII) ? bias[DII + j1] : 0.f;
        #pragma unroll
        for (int mi = 0; mi < 8; ++mi) {
            #pragma unroll
            for (int e = 0; e < 4; ++e) {
                int row = m0 + wm + mi * 16 + quad * 4 + e;
                if (row < nrow) {
                    bf16* cr = (bf16*)C + (size_t)row * ldc;
                    cr[j0] = __float2bfloat16(
                        glu_fast(acc[mi][0][e] + ba0, acc[mi][1][e] + bg0));
                    cr[j1] = __float2bfloat16(
                        glu_fast(acc[mi][2][e] + ba1, acc[mi][3][e] + bg1));
                }
            }
        }
    }
}

// ---------------- MFMA bf16 GEMM (small): C[nrow,M] = A @ Bt^T ----------------
// TM x 128 tile, BK=32, double-buffered, granule swizzle kc' = kc^((m>>1)&3).
// 4 waves. EPI 3 = fp32 accumulate (+= into C), optional PERM store.
template<int EPI, int PERM, int TM>
__global__ __launch_bounds__(256)
void mfma_gemm(const bf16* __restrict__ A, int lda,
               const bf16* __restrict__ Bt, int ldb,
               const float* __restrict__ bias,
               void* __restrict__ C, int ldc, int Mstore,
               int nrow, int K) {
    constexpr int MI = TM / 32;
    constexpr int ALW = TM / 64;
    __shared__ __align__(16) short lds_a[2][TM * 32];
    __shared__ __align__(16) short lds_b[2][128 * 32];
    int tid = threadIdx.x;
    int wave = tid >> 6, lane = tid & 63;
    int quad = lane >> 4, l16 = lane & 15;
    int m0 = blockIdx.y * TM, n0 = blockIdx.x * 128;
    int wm = (wave & 1) * (TM / 2), wn = (wave >> 1) * 64;
    f32x4 zero4 = {0.f, 0.f, 0.f, 0.f};
    f32x4 acc[MI][4];
    #pragma unroll
    for (int i = 0; i < MI; ++i)
        #pragma unroll
        for (int j = 0; j < 4; ++j) acc[i][j] = zero4;

    const short* Ap = (const short*)A;
    const short* Bp = (const short*)Bt;
    auto aptr = [&](int g) {
        int m = g >> 2, kc = (g & 3) ^ ((g >> 3) & 3);
        int r = m0 + m; if (r >= nrow) r = nrow - 1;
        return Ap + (size_t)r * lda + kc * 8;
    };
    auto bptr = [&](int g) {
        int m = g >> 2, kc = (g & 3) ^ ((g >> 3) & 3);
        return Bp + (size_t)(n0 + m) * ldb + kc * 8;
    };
    const short* gA[ALW]; int aoff[ALW];
    #pragma unroll
    for (int j = 0; j < ALW; ++j) {
        gA[j] = aptr(wave * TM + j * 64 + lane);
        aoff[j] = (wave * TM + j * 64) * 8;
    }
    const short* gB0 = bptr(wave * 128 + lane);
    const short* gB1 = bptr(wave * 128 + 64 + lane);
    int boff0 = (wave * 128) * 8, boff1 = (wave * 128 + 64) * 8;

    auto stage = [&](int buf, int kt) {
        int ko = kt * 32;
        #pragma unroll
        for (int j = 0; j < ALW; ++j)
            async16(gA[j] + ko, &lds_a[buf][aoff[j]]);
        async16(gB0 + ko, &lds_b[buf][boff0]);
        async16(gB1 + ko, &lds_b[buf][boff1]);
    };

    int nk = K >> 5;
    stage(0, 0);
    for (int kt = 0; kt < nk; ++kt) {
        int buf = kt & 1;
        __syncthreads();
        if (kt + 1 < nk) stage(buf ^ 1, kt + 1);
        short8 af[MI], bfr[4];
        #pragma unroll
        for (int mi = 0; mi < MI; ++mi) {
            int m = wm + mi * 16 + l16;
            af[mi] = *(const short8*)&lds_a[buf][(m * 4 + (quad ^ ((m >> 1) & 3))) * 8];
        }
        #pragma unroll
        for (int nj = 0; nj < 4; ++nj) {
            int n = wn + nj * 16 + l16;
            bfr[nj] = *(const short8*)&lds_b[buf][(n * 4 + (quad ^ ((n >> 1) & 3))) * 8];
        }
        #pragma unroll
        for (int mi = 0; mi < MI; ++mi)
            #pragma unroll
            for (int nj = 0; nj < 4; ++nj)
                acc[mi][nj] = __builtin_amdgcn_mfma_f32_16x16x32_bf16(
                    af[mi], bfr[nj], acc[mi][nj], 0, 0, 0);
    }

    #pragma unroll
    for (int mi = 0; mi < MI; ++mi) {
        #pragma unroll
        for (int e = 0; e < 4; ++e) {
            int row = m0 + wm + mi * 16 + quad * 4 + e;
            if (row >= nrow) continue;
            int orow = row;
            if (PERM) {
                int t = row & 15; int rs = row >> 4; int s = rs % SSQ; int b = rs / SSQ;
                orow = (b * TT + t) * SSQ + s;
            }
            #pragma unroll
            for (int nj = 0; nj < 4; ++nj) {
                int col = n0 + wn + nj * 16 + l16;
                if (col >= Mstore) continue;
                float v = acc[mi][nj][e];
                if (bias) v += bias[col];
                ((float*)C)[(size_t)orow * ldc + col] += v;
            }
        }
    }
}

// ---------------- V transpose for PV MFMA: vt[bt*8+kh][64][SKP] bf16 ----------------
__global__ void vtrans_kernel(const bf16* __restrict__ qkv, bf16* __restrict__ vt) {
    int bkh = blockIdx.x;          // bt*8 + kh
    int kc = blockIdx.y;           // key chunk of 32
    int bt = bkh >> 3, kh = bkh & 7;
    int tid = threadIdx.x;
    #pragma unroll
    for (int i = 0; i < 8; ++i) {
        int idx = tid + 256 * i;   // 0..2047
        int kl = idx >> 6;         // key local
        int d = idx & 63;
        int key = kc * 32 + kl;
        float v = 0.f;
        if (key < SSQ)
            v = __bfloat162float(qkv[((size_t)(bt * SSQ + key)) * 2048 + 1536 + kh * 64 + d]);
        vt[((size_t)bkh * 64 + d) * SKP + key] = __float2bfloat16(v);
    }
}

// ---------------- space attention: S^T in registers, K staged in LDS ----------------
__global__ __launch_bounds__(256)
void space_attn_kernel(const bf16* __restrict__ qkv, const bf16* __restrict__ vt,
                       bf16* __restrict__ ob) {
    __shared__ __align__(16) short kls[272 * 8 * 8];   // granule (key,c): K[key][8*(c^(key&7))..+8)
    int qt = blockIdx.x, qh = blockIdx.y, bt = blockIdx.z;
    int kh = qh >> 1;
    int tid = threadIdx.x, wave = tid >> 6, lane = tid & 63;
    int quad = lane >> 4, l16 = lane & 15;
    int q0w = qt * 64 + wave * 16;
    int q = q0w + l16;
    int qc = q > 256 ? 256 : q;
    const short* qbase = (const short*)qkv + (size_t)bt * SSQ * 2048;

    const short* kgbase = qbase + 1024 + kh * 64;
    #pragma unroll
    for (int it = 0; it < 9; ++it) {
        int u = it * 4 + wave;
        if (u < 34) {
            int g = u * 64 + lane;
            int key = g >> 3, ch = g & 7;
            int srck = key < SSQ ? key : 256;
            async16(kgbase + (size_t)srck * 2048 + (ch ^ (key & 7)) * 8,
                    &kls[u * 512]);
        }
    }

    const short* qp = qbase + (size_t)qc * 2048 + qh * 64;
    short8 bq0 = *(const short8*)(qp + quad * 8);
    short8 bq1 = *(const short8*)(qp + 32 + quad * 8);
    __syncthreads();   // drains vmcnt: K staged

    f32x4 zero4 = {0.f, 0.f, 0.f, 0.f};
    f32x4 sc[18];
    float sum = 0.f;
    int c0 = quad ^ (l16 & 7);   // key&7 == l16&7 since kt*16 % 8 == 0
    #pragma unroll
    for (int kt = 0; kt < 17; ++kt) {
        int key = kt * 16 + l16;
        short8 ak0 = *(const short8*)&kls[(key * 8 + c0) * 8];
        short8 ak1 = *(const short8*)&kls[(key * 8 + (c0 ^ 4)) * 8];
        f32x4 cc = zero4;
        cc = __builtin_amdgcn_mfma_f32_16x16x32_bf16(ak0, bq0, cc, 0, 0, 0);
        cc = __builtin_amdgcn_mfma_f32_16x16x32_bf16(ak1, bq1, cc, 0, 0, 0);
        #pragma unroll
        for (int e = 0; e < 4; ++e) {
            float x = cc[e] * 0.0025f;           // s/50, s = dot/8
            float x2 = x * x;
            float v = cc[e] * 0.125f * (1.f + x2 * (-0.3333333333f + x2 * 0.1333333333f));
            float p = __expf(v);                 // v in [-8.1, 8.1]: no overflow
            if (kt == 16) {
                bool valid = (e == 0) && (quad == 0) && (q == 256);
                p = valid ? p : 0.f;
            }
            cc[e] = p;
            sum += p;
        }
        sc[kt] = cc;
    }
    #pragma unroll
    for (int e = 0; e < 4; ++e) sc[17][e] = 0.f;
    sum += __shfl_xor(sum, 16);
    sum += __shfl_xor(sum, 32);
    float inv = __builtin_amdgcn_rcpf(sum);
    f32x4 inv4;
    #pragma unroll
    for (int e = 0; e < 4; ++e) inv4[e] = __shfl(inv, quad * 4 + e);

    f32x4 oacc[4];
    #pragma unroll
    for (int nt = 0; nt < 4; ++nt) oacc[nt] = zero4;
    const short* vbp = (const short*)vt + ((size_t)(bt * 8 + kh) * 64 + l16) * SKP;
    #pragma unroll
    for (int c8 = 0; c8 < 9; ++c8) {
        short8 pb;
        #pragma unroll
        for (int j = 0; j < 8; ++j) {
            int src_lane = ((quad & 1) * 2 + (j >> 2)) * 16 + l16;
            float v0 = __shfl(sc[2 * c8][j & 3], src_lane);
            float v1 = __shfl(sc[2 * c8 + 1][j & 3], src_lane);
            pb[j] = f2bfs(quad < 2 ? v0 : v1);
        }
        #pragma unroll
        for (int nt = 0; nt < 4; ++nt) {
            short8 av = *(const short8*)(vbp + (size_t)(nt * 16) * SKP + c8 * 32 + quad * 8);
            oacc[nt] = __builtin_amdgcn_mfma_f32_16x16x32_bf16(pb, av, oacc[nt], 0, 0, 0);
        }
    }

    #pragma unroll
    for (int e = 0; e < 4; ++e) {
        int qq = q0w + quad * 4 + e;
        if (qq <= 256) {
            bf16* op = ob + ((size_t)(bt * SSQ + qq)) * 1024 + qh * 64 + l16;
            float s = inv4[e];
            op[0]  = __float2bfloat16(oacc[0][e] * s);
            op[16] = __float2bfloat16(oacc[1][e] * s);
            op[32] = __float2bfloat16(oacc[2][e] * s);
            op[48] = __float2bfloat16(oacc[3][e] * s);
        }
    }
}

// ---------------- time attention (n=16, causal): one block per (b*s, qh) ----------------
__global__ void time_attn_kernel(const bf16* __restrict__ qkv, bf16* __restrict__ ob) {
    __shared__ float qs[16][65], ks[16][65], ps[16][17];
    int bs = blockIdx.x, qh = blockIdx.y, kh = qh >> 1;
    int tid = threadIdx.x;
    size_t rowbase = (size_t)bs * 16;
    #pragma unroll
    for (int i = 0; i < 4; ++i) {
        int idx = tid + 256 * i;
        int r = idx >> 6, d = idx & 63;
        qs[r][d] = __bfloat162float(qkv[(rowbase + r) * 2048 + qh * 64 + d]);
        ks[r][d] = __bfloat162float(qkv[(rowbase + r) * 2048 + 1024 + kh * 64 + d]);
    }
    __syncthreads();
    int i = tid >> 4, j = tid & 15;
    float dot = 0.f;
    #pragma unroll 16
    for (int d = 0; d < 64; ++d) dot += qs[i][d] * ks[j][d];
    float s = dot * 0.125f;
    float x = s * 0.02f;
    float x2 = x * x;
    float v = s * (1.f + x2 * (-0.3333333333f + x2 * 0.1333333333f));
    float p = (j > i) ? 0.f : __expf(v);
    float sum = p;
    sum += __shfl_xor(sum, 1);
    sum += __shfl_xor(sum, 2);
    sum += __shfl_xor(sum, 4);
    sum += __shfl_xor(sum, 8);
    ps[i][j] = p * __builtin_amdgcn_rcpf(sum);
    __syncthreads();
    #pragma unroll
    for (int ii = 0; ii < 4; ++ii) {
        int idx = tid + 256 * ii;
        int r = idx >> 6, d = idx & 63;
        float acc = 0.f;
        #pragma unroll
        for (int jj = 0; jj < 16; ++jj)
            acc += ps[r][jj] * __bfloat162float(qkv[(rowbase + jj) * 2048 + 1536 + kh * 64 + d]);
        ob[(rowbase + r) * 1024 + qh * 64 + d] = __float2bfloat16(acc);
    }
}

// ---------------- host-side launch ----------------
extern "C" void kernel_launch(void* const* d_in, const int* in_sizes, int n_in,
                              void* d_out, int out_size, void* d_ws, size_t ws_size,
                              hipStream_t stream) {
    const float* tokens      = (const float*)d_in[0];
    const float* attn_norm_w = (const float*)d_in[1];
    const float* Wq          = (const float*)d_in[2];
    const float* Wk          = (const float*)d_in[3];
    const float* Wv          = (const float*)d_in[4];
    const float* q_gamma     = (const float*)d_in[5];
    const float* k_gamma     = (const float*)d_in[6];
    const float* Wo          = (const float*)d_in[7];
    const float* ff_norm_w   = (const float*)d_in[8];
    const float* W_in        = (const float*)d_in[9];
    const float* b_in        = (const float*)d_in[10];
    const float* W_out       = (const float*)d_in[11];
    const float* b_out       = (const float*)d_in[12];
    const float* final_w     = (const float*)d_in[13];

    float* x = (float*)d_out;
    char* ws = (char*)d_ws;

    bf16* wtqkv = (bf16*)ws;                     // [2048][512]
    bf16* wto   = wtqkv + 2048 * 512;            // [512][1024]
    bf16* wtin  = wto   + 512 * 1024;            // [2816][512] interleaved
    bf16* wtout = wtin  + 2816 * 512;            // [512][1408]
    size_t off = (size_t)(2048*512 + 512*1024 + 2816*512 + 512*1408) * 2;
    bf16* h = (bf16*)(ws + off);                 // [N][512]
    off += (size_t)NROWS * 512 * 2;
    char* region = ws + off;
    bf16* qkv = (bf16*)region;                               // [N][2048]
    bf16* glu = (bf16*)region;                               // [N][1408] (FF alias)
    bf16* vt  = (bf16*)(region + (size_t)NROWS * 2048 * 2);  // [256][64][288]
    bf16* ob  = (bf16*)(region + (size_t)NROWS * 2048 * 2 + (size_t)256*64*SKP*2);  // [N][1024]

    hipMemcpyAsync(x, tokens, (size_t)NROWS * 512 * 4, hipMemcpyDeviceToDevice, stream);

    for (int l = 0; l < 8; ++l) {
        int is_time = ((l + 1) % 4 == 0) ? 1 : 0;
        wtrans_layer<<<3648, 256, 0, stream>>>(
            Wq + (size_t)l * 512 * 1024, Wk + (size_t)l * 512 * 512,
            Wv + (size_t)l * 512 * 512, Wo + (size_t)l * 1024 * 512,
            W_in + (size_t)l * 512 * DI2, W_out + (size_t)l * DII * 512,
            wtqkv, wto, wtin, wtout);

        // ---- attention block ----
        rms_kernel<1><<<2056, 256, 0, stream>>>(x, attn_norm_w + (size_t)l * 512, h, is_time);
        mfma_gemm_big<1><<<dim3(8, 33), 512, 0, stream>>>(
            h, 512, wtqkv, 512, nullptr, qkv, 2048, NROWS, 512,
            q_gamma + (size_t)l * 1024, k_gamma + (size_t)l * 512, is_time);
        if (is_time) {
            time_attn_kernel<<<dim3(514, 16), 256, 0, stream>>>(qkv, ob);
            mfma_gemm<3, 1, 64><<<dim3(4, 129), 256, 0, stream>>>(
                ob, 1024, wto, 1024, nullptr, x, 512, 512, NROWS, 1024);
        } else {
            vtrans_kernel<<<dim3(256, 9), 256, 0, stream>>>(qkv, vt);
            space_attn_kernel<<<dim3(5, 16, 32), 256, 0, stream>>>(qkv, vt, ob);
            mfma_gemm<3, 0, 64><<<dim3(4, 129), 256, 0, stream>>>(
                ob, 1024, wto, 1024, nullptr, x, 512, 512, NROWS, 1024);
        }

        // ---- feed-forward block ----
        rms_kernel<1><<<2056, 256, 0, stream>>>(x, ff_norm_w + (size_t)l * 512, h, 0);
        mfma_gemm_big<2><<<dim3(11, 33), 512, 0, stream>>>(
            h, 512, wtin, 512, b_in + (size_t)l * DI2, glu, GLULD, NROWS, 512,
            nullptr, nullptr, 0);
        mfma_gemm<3, 0, 64><<<dim3(4, 129), 256, 0, stream>>>(
            glu, GLULD, wtout, GLULD, b_out + (size_t)l * 512, x, 512, 512, NROWS, GLULD);
    }

    rms_kernel<0><<<2056, 256, 0, stream>>>(x, final_w, x, 0);
}

// Round 6
// 2057.190 us; speedup vs baseline: 1.3097x; 1.1192x over previous
//
#include <hip/hip_runtime.h>
#include <hip/hip_bf16.h>
#include <math.h>

typedef __attribute__((ext_vector_type(8))) short short8;
typedef __attribute__((ext_vector_type(4))) float f32x4;
typedef __hip_bfloat16 bf16;

#define BB 2
#define TT 16
#define SSQ 257
#define DIMD 512
#define NROWS 8224          // B*T*S
#define DII 1365
#define DI2 2730
#define FNPAD 2816          // ff_in N padded (22*128), block-16 interleaved a/g
#define GLULD 1408          // glu row stride / ff_out K (44*32)
#define SKP 288             // padded key count for space attn
#define EPSR 1.1920929e-07f

__device__ __forceinline__ void async16(const void* g, const void* l) {
    __builtin_amdgcn_global_load_lds(
        (const __attribute__((address_space(1))) void*)g,
        (__attribute__((address_space(3))) void*)l, 16, 0, 0);
}

__device__ __forceinline__ short f2bfs(float x) {
    bf16 h = __float2bfloat16(x);
    return *reinterpret_cast<short*>(&h);
}

// fast exact-gelu: a * g * Phi(g), erf via A&S 7.1.26 (abs err 1.5e-7)
__device__ __forceinline__ float glu_fast(float a, float g) {
    float x = g * 0.70710678118654752f;
    float ax = fabsf(x);
    float t = __builtin_amdgcn_rcpf(__builtin_fmaf(0.3275911f, ax, 1.f));
    float p = t * (0.254829592f + t * (-0.284496736f + t * (1.421413741f
              + t * (-1.453152027f + t * 1.061405429f))));
    float erfv = 1.f - p * __expf(-ax * ax);
    erfv = (x < 0.f) ? -erfv : erfv;
    return a * 0.5f * g * (1.f + erfv);
}

// ---------------- batched per-layer weight transpose fp32->bf16 ----------------
// win interleave: a_j -> col (j>>4)*32 + (j&15); g_j -> col (j>>4)*32 + 16 + (j&15)
__global__ void wtrans_layer(const float* __restrict__ wq, const float* __restrict__ wk,
                             const float* __restrict__ wv, const float* __restrict__ wo,
                             const float* __restrict__ win, const float* __restrict__ wout,
                             bf16* __restrict__ dqkv, bf16* __restrict__ dwo,
                             bf16* __restrict__ dwin, bf16* __restrict__ dwout) {
    __shared__ float tile[32][33];
    int bid = blockIdx.x;
    const float* src; bf16* dst; int K, M, Kpad, interleave = 0, local;
    if (bid < 512)       { src = wq;   dst = dqkv;            K = 512;  M = 1024; Kpad = 512;  local = bid; }
    else if (bid < 768)  { src = wk;   dst = dqkv + 1024*512; K = 512;  M = 512;  Kpad = 512;  local = bid - 512; }
    else if (bid < 1024) { src = wv;   dst = dqkv + 1536*512; K = 512;  M = 512;  Kpad = 512;  local = bid - 768; }
    else if (bid < 1536) { src = wo;   dst = dwo;             K = 1024; M = 512;  Kpad = 1024; local = bid - 1024; }
    else if (bid < 2944) { src = win;  dst = dwin;            K = 512;  M = 2730; Kpad = 512;  local = bid - 1536; interleave = 1; }
    else                 { src = wout; dst = dwout;           K = 1365; M = 512;  Kpad = 1408; local = bid - 2944; }
    int tilesx = Kpad >> 5;
    int k0 = (local % tilesx) * 32, m0 = (local / tilesx) * 32;
    int tx = threadIdx.x & 31, ty = threadIdx.x >> 5;
    #pragma unroll
    for (int i = 0; i < 4; ++i) {
        int k = k0 + ty + 8 * i, m = m0 + tx;
        tile[ty + 8 * i][tx] = (k < K && m < M) ? src[(size_t)k * M + m] : 0.f;
    }
    __syncthreads();
    #pragma unroll
    for (int i = 0; i < 4; ++i) {
        int n = m0 + ty + 8 * i, k = k0 + tx;
        int nd = n;
        if (interleave) {
            if (n < DII)        nd = ((n >> 4) << 5) + (n & 15);
            else if (n < DI2) { int m = n - DII; nd = ((m >> 4) << 5) + 16 + (m & 15); }
            else              { int q = n - DI2; int j = DII + (q >> 1);
                                nd = ((j >> 4) << 5) + ((q & 1) << 4) + (j & 15); }
        }
        dst[(size_t)nd * Kpad + k] = __float2bfloat16(tile[tx][ty + 8 * i]);
    }
}

// ---------------- RMSNorm: one wave per row, float4 loads, shuffle reduce ----------------
template<int BF16OUT>
__global__ __launch_bounds__(256)
void rms_kernel(const float* __restrict__ x, const float* __restrict__ w,
                void* __restrict__ out, int perm) {
    int wave = threadIdx.x >> 6, lane = threadIdx.x & 63;
    int r = blockIdx.x * 4 + wave;
    int src = r;
    if (perm) {
        int t = r & 15; int rs = r >> 4; int s = rs % SSQ; int b = rs / SSQ;
        src = (b * TT + t) * SSQ + s;
    }
    const float4* xr = (const float4*)(x + (size_t)src * DIMD) + lane * 2;
    float4 a = xr[0], c = xr[1];
    float ss = a.x*a.x + a.y*a.y + a.z*a.z + a.w*a.w
             + c.x*c.x + c.y*c.y + c.z*c.z + c.w*c.w;
    ss += __shfl_xor(ss, 1);  ss += __shfl_xor(ss, 2);  ss += __shfl_xor(ss, 4);
    ss += __shfl_xor(ss, 8);  ss += __shfl_xor(ss, 16); ss += __shfl_xor(ss, 32);
    float sc = rsqrtf(ss * (1.f / DIMD) + EPSR);
    const float4* wr = (const float4*)w + lane * 2;
    float4 wa = wr[0], wb = wr[1];
    if (BF16OUT) {
        short8 v;
        v[0] = f2bfs(a.x * sc * wa.x); v[1] = f2bfs(a.y * sc * wa.y);
        v[2] = f2bfs(a.z * sc * wa.z); v[3] = f2bfs(a.w * sc * wa.w);
        v[4] = f2bfs(c.x * sc * wb.x); v[5] = f2bfs(c.y * sc * wb.y);
        v[6] = f2bfs(c.z * sc * wb.z); v[7] = f2bfs(c.w * sc * wb.w);
        *(short8*)((bf16*)out + (size_t)r * DIMD + lane * 8) = v;
    } else {
        float4* o = (float4*)((float*)out + (size_t)r * DIMD) + lane * 2;
        float4 o0 = {a.x * sc * wa.x, a.y * sc * wa.y, a.z * sc * wa.z, a.w * sc * wa.w};
        float4 o1 = {c.x * sc * wb.x, c.y * sc * wb.y, c.z * sc * wb.z, c.w * sc * wb.w};
        o[0] = o0; o[1] = o1;
    }
}

// ---------------- panel MFMA GEMM: B-panel resident in LDS, barrier-free loop --------
// Exploits K=512: a full 128-col B panel is 128x512x2B = 128KB = one LDS. Load it
// ONCE (transposed granule layout: granule (c,n) at gi=c*128+n holds B[n0+n][c*8..+8],
// so a wave's ds_read_b128 is 64 consecutive 16B granules -> zero bank conflicts and
// ~2 VALU/K-step of addressing), then NO barriers: each of 8 waves independently
// streams its m-frags, reading A direct from global (64B/row contiguous, L2/L3-hot,
// XCD-swizzled for A-panel locality), 1-deep A prefetch, 8 MFMA per K-step.
// Per-frag epilogue streams C while the next frag's loads issue.
// EPI: 1 = qkv + fused l2norm/gamma/rotary; 2 = glu (block-16 interleaved a/g).
template<int EPI>
__global__ __launch_bounds__(512, 1)
void mfma_gemm_panel(const bf16* __restrict__ A, int lda,
                     const bf16* __restrict__ Bt, int ldb,
                     const float* __restrict__ bias,
                     void* __restrict__ C, int ldc,
                     int nrow, int mchunk,
                     const float* __restrict__ qg, const float* __restrict__ kg,
                     int rotary) {
    __shared__ __align__(16) short lds_b[128 * 512];   // 128 KB
    // T1: bijective XCD-aware remap (m204)
    int gx = gridDim.x;
    int nwg = gx * gridDim.y;
    int lin = blockIdx.y * gx + blockIdx.x;
    int q8 = nwg >> 3, r8 = nwg & 7;
    int xcd = lin & 7, idx = lin >> 3;
    int wsw = (xcd < r8 ? xcd * (q8 + 1) : r8 * (q8 + 1) + (xcd - r8) * q8) + idx;
    int bx = wsw % gx, by = wsw / gx;
    int n0 = bx * 128, m0 = by * mchunk;

    int tid = threadIdx.x;
    int wave = tid >> 6, lane = tid & 63;
    int quad = lane >> 4, l16 = lane & 15;

    // stage B panel: 8192 granules of 16B; granule gi: c = gi>>7, n = gi&127
    const short* Bp = (const short*)Bt;
    #pragma unroll
    for (int j = 0; j < 16; ++j) {
        int gi = tid + 512 * j;
        int n = gi & 127, c = gi >> 7;
        async16(Bp + (size_t)(n0 + n) * ldb + c * 8, &lds_b[gi * 8]);
    }
    const short* Ap = (const short*)A;

    // hoisted epilogue constants
    float gl[2][4];
    float c0r[4], s0r[4], c1r[4], s1r[4];
    bool isqk = false;
    float ba[4], bg[4];
    if constexpr (EPI == 1) {
        int headb = n0 >> 6;
        isqk = headb < 24;
        if (isqk) {
            #pragma unroll
            for (int hh = 0; hh < 2; ++hh) {
                int head = headb + hh;
                const float* g = head < 16 ? qg + head * 64 : kg + (head - 16) * 64;
                gl[hh][0] = (g[l16] + 1.f) * 8.f;
                gl[hh][1] = (g[16 + l16] + 1.f) * 8.f;
                gl[hh][2] = (g[32 + l16] + 1.f) * 8.f;
                gl[hh][3] = (g[48 + l16] + 1.f) * 8.f;
            }
        }
        if (rotary) {
            float inv0 = __expf(-(float)l16 * 0.28782313662425572f);        // ln(1e4)/32
            float inv1 = __expf(-(float)(l16 + 16) * 0.28782313662425572f);
            #pragma unroll
            for (int e = 0; e < 4; ++e) {
                float t = (float)(quad * 4 + e);
                c0r[e] = __cosf(t * inv0); s0r[e] = __sinf(t * inv0);
                c1r[e] = __cosf(t * inv1); s1r[e] = __sinf(t * inv1);
            }
        }
    } else {
        int jb = n0 >> 1;
        #pragma unroll
        for (int t = 0; t < 4; ++t) {
            int j = jb + t * 16 + l16;
            ba[t] = (j < DII) ? bias[j] : 0.f;
            bg[t] = (j < DII) ? bias[DII + j] : 0.f;
        }
    }
    __syncthreads();   // B panel resident (drains vmcnt before barrier)

    int base_b = (quad * 128 + l16) * 16;   // byte addr of granule (c=quad, n=l16)
    int nfrag = mchunk >> 4;
    for (int f = wave; f < nfrag; f += 8) {
        int mrow = m0 + f * 16 + l16;
        if (mrow >= nrow) mrow = nrow - 1;          // clamp; C-write guarded below
        const short* ap = Ap + (size_t)mrow * lda + quad * 8;
        f32x4 acc[8];
        #pragma unroll
        for (int nj = 0; nj < 8; ++nj) acc[nj] = {0.f, 0.f, 0.f, 0.f};
        short8 a = *(const short8*)ap;
        short8 anext = a;
        #pragma unroll
        for (int kt = 0; kt < 16; ++kt) {
            if (kt < 15) anext = *(const short8*)(ap + (kt + 1) * 32);
            const char* vb = (const char*)lds_b + base_b + kt * 8192;
            __builtin_amdgcn_s_setprio(1);
            #pragma unroll
            for (int nj = 0; nj < 8; ++nj) {
                short8 b = *(const short8*)(vb + nj * 256);
                acc[nj] = __builtin_amdgcn_mfma_f32_16x16x32_bf16(a, b, acc[nj], 0, 0, 0);
            }
            __builtin_amdgcn_s_setprio(0);
            a = anext;
        }
        if constexpr (EPI == 1) {
            #pragma unroll
            for (int hh = 0; hh < 2; ++hh) {
                #pragma unroll
                for (int e = 0; e < 4; ++e) {
                    int row = m0 + f * 16 + quad * 4 + e;
                    float v0 = acc[hh * 4 + 0][e], v1 = acc[hh * 4 + 1][e];
                    float v2 = acc[hh * 4 + 2][e], v3 = acc[hh * 4 + 3][e];
                    if (isqk) {
                        float ss = v0 * v0 + v1 * v1 + v2 * v2 + v3 * v3;
                        ss += __shfl_xor(ss, 1); ss += __shfl_xor(ss, 2);
                        ss += __shfl_xor(ss, 4); ss += __shfl_xor(ss, 8);
                        float invn = 1.f / fmaxf(sqrtf(ss), 1e-12f);
                        v0 *= invn * gl[hh][0]; v1 *= invn * gl[hh][1];
                        v2 *= invn * gl[hh][2]; v3 *= invn * gl[hh][3];
                        if (rotary) {
                            float n0v = v0 * c0r[e] - v2 * s0r[e];
                            float n1v = v1 * c1r[e] - v3 * s1r[e];
                            float n2v = v2 * c0r[e] + v0 * s0r[e];
                            float n3v = v3 * c1r[e] + v1 * s1r[e];
                            v0 = n0v; v1 = n1v; v2 = n2v; v3 = n3v;
                        }
                    }
                    if (row < nrow) {
                        bf16* p = (bf16*)C + (size_t)row * ldc + n0 + hh * 64 + l16;
                        p[0]  = __float2bfloat16(v0);
                        p[16] = __float2bfloat16(v1);
                        p[32] = __float2bfloat16(v2);
                        p[48] = __float2bfloat16(v3);
                    }
                }
            }
        } else {
            int jb = n0 >> 1;
            #pragma unroll
            for (int e = 0; e < 4; ++e) {
                int row = m0 + f * 16 + quad * 4 + e;
                if (row < nrow) {
                    bf16* cr = (bf16*)C + (size_t)row * ldc;
                    #pragma unroll
                    for (int t = 0; t < 4; ++t)
                        cr[jb + t * 16 + l16] = __float2bfloat16(
                            glu_fast(acc[2 * t][e] + ba[t], acc[2 * t + 1][e] + bg[t]));
                }
            }
        }
    }
}

// ---------------- MFMA bf16 GEMM (small): C[nrow,M] = A @ Bt^T ----------------
// TM x 128 tile, BK=32, double-buffered, granule swizzle kc' = kc^((m>>1)&3).
// 4 waves. EPI 3 = fp32 accumulate (+= into C), optional PERM store.
template<int EPI, int PERM, int TM>
__global__ __launch_bounds__(256)
void mfma_gemm(const bf16* __restrict__ A, int lda,
               const bf16* __restrict__ Bt, int ldb,
               const float* __restrict__ bias,
               void* __restrict__ C, int ldc, int Mstore,
               int nrow, int K) {
    constexpr int MI = TM / 32;
    constexpr int ALW = TM / 64;
    __shared__ __align__(16) short lds_a[2][TM * 32];
    __shared__ __align__(16) short lds_b[2][128 * 32];
    int tid = threadIdx.x;
    int wave = tid >> 6, lane = tid & 63;
    int quad = lane >> 4, l16 = lane & 15;
    int m0 = blockIdx.y * TM, n0 = blockIdx.x * 128;
    int wm = (wave & 1) * (TM / 2), wn = (wave >> 1) * 64;
    f32x4 zero4 = {0.f, 0.f, 0.f, 0.f};
    f32x4 acc[MI][4];
    #pragma unroll
    for (int i = 0; i < MI; ++i)
        #pragma unroll
        for (int j = 0; j < 4; ++j) acc[i][j] = zero4;

    const short* Ap = (const short*)A;
    const short* Bp = (const short*)Bt;
    auto aptr = [&](int g) {
        int m = g >> 2, kc = (g & 3) ^ ((g >> 3) & 3);
        int r = m0 + m; if (r >= nrow) r = nrow - 1;
        return Ap + (size_t)r * lda + kc * 8;
    };
    auto bptr = [&](int g) {
        int m = g >> 2, kc = (g & 3) ^ ((g >> 3) & 3);
        return Bp + (size_t)(n0 + m) * ldb + kc * 8;
    };
    const short* gA[ALW]; int aoff[ALW];
    #pragma unroll
    for (int j = 0; j < ALW; ++j) {
        gA[j] = aptr(wave * TM + j * 64 + lane);
        aoff[j] = (wave * TM + j * 64) * 8;
    }
    const short* gB0 = bptr(wave * 128 + lane);
    const short* gB1 = bptr(wave * 128 + 64 + lane);
    int boff0 = (wave * 128) * 8, boff1 = (wave * 128 + 64) * 8;

    auto stage = [&](int buf, int kt) {
        int ko = kt * 32;
        #pragma unroll
        for (int j = 0; j < ALW; ++j)
            async16(gA[j] + ko, &lds_a[buf][aoff[j]]);
        async16(gB0 + ko, &lds_b[buf][boff0]);
        async16(gB1 + ko, &lds_b[buf][boff1]);
    };

    int nk = K >> 5;
    stage(0, 0);
    for (int kt = 0; kt < nk; ++kt) {
        int buf = kt & 1;
        __syncthreads();
        if (kt + 1 < nk) stage(buf ^ 1, kt + 1);
        short8 af[MI], bfr[4];
        #pragma unroll
        for (int mi = 0; mi < MI; ++mi) {
            int m = wm + mi * 16 + l16;
            af[mi] = *(const short8*)&lds_a[buf][(m * 4 + (quad ^ ((m >> 1) & 3))) * 8];
        }
        #pragma unroll
        for (int nj = 0; nj < 4; ++nj) {
            int n = wn + nj * 16 + l16;
            bfr[nj] = *(const short8*)&lds_b[buf][(n * 4 + (quad ^ ((n >> 1) & 3))) * 8];
        }
        #pragma unroll
        for (int mi = 0; mi < MI; ++mi)
            #pragma unroll
            for (int nj = 0; nj < 4; ++nj)
                acc[mi][nj] = __builtin_amdgcn_mfma_f32_16x16x32_bf16(
                    af[mi], bfr[nj], acc[mi][nj], 0, 0, 0);
    }

    #pragma unroll
    for (int mi = 0; mi < MI; ++mi) {
        #pragma unroll
        for (int e = 0; e < 4; ++e) {
            int row = m0 + wm + mi * 16 + quad * 4 + e;
            if (row >= nrow) continue;
            int orow = row;
            if (PERM) {
                int t = row & 15; int rs = row >> 4; int s = rs % SSQ; int b = rs / SSQ;
                orow = (b * TT + t) * SSQ + s;
            }
            #pragma unroll
            for (int nj = 0; nj < 4; ++nj) {
                int col = n0 + wn + nj * 16 + l16;
                if (col >= Mstore) continue;
                float v = acc[mi][nj][e];
                if (bias) v += bias[col];
                ((float*)C)[(size_t)orow * ldc + col] += v;
            }
        }
    }
}

// ---------------- V transpose for PV MFMA: vt[bt*8+kh][64][SKP] bf16 ----------------
__global__ void vtrans_kernel(const bf16* __restrict__ qkv, bf16* __restrict__ vt) {
    int bkh = blockIdx.x;          // bt*8 + kh
    int kc = blockIdx.y;           // key chunk of 32
    int bt = bkh >> 3, kh = bkh & 7;
    int tid = threadIdx.x;
    #pragma unroll
    for (int i = 0; i < 8; ++i) {
        int idx = tid + 256 * i;   // 0..2047
        int kl = idx >> 6;         // key local
        int d = idx & 63;
        int key = kc * 32 + kl;
        float v = 0.f;
        if (key < SSQ)
            v = __bfloat162float(qkv[((size_t)(bt * SSQ + key)) * 2048 + 1536 + kh * 64 + d]);
        vt[((size_t)bkh * 64 + d) * SKP + key] = __float2bfloat16(v);
    }
}

// ---------------- space attention: S^T in registers, K staged in LDS ----------------
__global__ __launch_bounds__(256)
void space_attn_kernel(const bf16* __restrict__ qkv, const bf16* __restrict__ vt,
                       bf16* __restrict__ ob) {
    __shared__ __align__(16) short kls[272 * 8 * 8];   // granule (key,c): K[key][8*(c^(key&7))..+8)
    int qt = blockIdx.x, qh = blockIdx.y, bt = blockIdx.z;
    int kh = qh >> 1;
    int tid = threadIdx.x, wave = tid >> 6, lane = tid & 63;
    int quad = lane >> 4, l16 = lane & 15;
    int q0w = qt * 64 + wave * 16;
    int q = q0w + l16;
    int qc = q > 256 ? 256 : q;
    const short* qbase = (const short*)qkv + (size_t)bt * SSQ * 2048;

    const short* kgbase = qbase + 1024 + kh * 64;
    #pragma unroll
    for (int it = 0; it < 9; ++it) {
        int u = it * 4 + wave;
        if (u < 34) {
            int g = u * 64 + lane;
            int key = g >> 3, ch = g & 7;
            int srck = key < SSQ ? key : 256;
            async16(kgbase + (size_t)srck * 2048 + (ch ^ (key & 7)) * 8,
                    &kls[u * 512]);
        }
    }

    const short* qp = qbase + (size_t)qc * 2048 + qh * 64;
    short8 bq0 = *(const short8*)(qp + quad * 8);
    short8 bq1 = *(const short8*)(qp + 32 + quad * 8);
    __syncthreads();   // drains vmcnt: K staged

    f32x4 zero4 = {0.f, 0.f, 0.f, 0.f};
    f32x4 sc[18];
    float sum = 0.f;
    int c0 = quad ^ (l16 & 7);   // key&7 == l16&7 since kt*16 % 8 == 0
    #pragma unroll
    for (int kt = 0; kt < 17; ++kt) {
        int key = kt * 16 + l16;
        short8 ak0 = *(const short8*)&kls[(key * 8 + c0) * 8];
        short8 ak1 = *(const short8*)&kls[(key * 8 + (c0 ^ 4)) * 8];
        f32x4 cc = zero4;
        cc = __builtin_amdgcn_mfma_f32_16x16x32_bf16(ak0, bq0, cc, 0, 0, 0);
        cc = __builtin_amdgcn_mfma_f32_16x16x32_bf16(ak1, bq1, cc, 0, 0, 0);
        #pragma unroll
        for (int e = 0; e < 4; ++e) {
            float x = cc[e] * 0.0025f;           // s/50, s = dot/8
            float x2 = x * x;
            float v = cc[e] * 0.125f * (1.f + x2 * (-0.3333333333f + x2 * 0.1333333333f));
            float p = __expf(v);                 // v in [-8.1, 8.1]: no overflow
            if (kt == 16) {
                bool valid = (e == 0) && (quad == 0) && (q == 256);
                p = valid ? p : 0.f;
            }
            cc[e] = p;
            sum += p;
        }
        sc[kt] = cc;
    }
    #pragma unroll
    for (int e = 0; e < 4; ++e) sc[17][e] = 0.f;
    sum += __shfl_xor(sum, 16);
    sum += __shfl_xor(sum, 32);
    float inv = __builtin_amdgcn_rcpf(sum);
    f32x4 inv4;
    #pragma unroll
    for (int e = 0; e < 4; ++e) inv4[e] = __shfl(inv, quad * 4 + e);

    f32x4 oacc[4];
    #pragma unroll
    for (int nt = 0; nt < 4; ++nt) oacc[nt] = zero4;
    const short* vbp = (const short*)vt + ((size_t)(bt * 8 + kh) * 64 + l16) * SKP;
    #pragma unroll
    for (int c8 = 0; c8 < 9; ++c8) {
        short8 pb;
        #pragma unroll
        for (int j = 0; j < 8; ++j) {
            int src_lane = ((quad & 1) * 2 + (j >> 2)) * 16 + l16;
            float v0 = __shfl(sc[2 * c8][j & 3], src_lane);
            float v1 = __shfl(sc[2 * c8 + 1][j & 3], src_lane);
            pb[j] = f2bfs(quad < 2 ? v0 : v1);
        }
        #pragma unroll
        for (int nt = 0; nt < 4; ++nt) {
            short8 av = *(const short8*)(vbp + (size_t)(nt * 16) * SKP + c8 * 32 + quad * 8);
            oacc[nt] = __builtin_amdgcn_mfma_f32_16x16x32_bf16(pb, av, oacc[nt], 0, 0, 0);
        }
    }

    #pragma unroll
    for (int e = 0; e < 4; ++e) {
        int qq = q0w + quad * 4 + e;
        if (qq <= 256) {
            bf16* op = ob + ((size_t)(bt * SSQ + qq)) * 1024 + qh * 64 + l16;
            float s = inv4[e];
            op[0]  = __float2bfloat16(oacc[0][e] * s);
            op[16] = __float2bfloat16(oacc[1][e] * s);
            op[32] = __float2bfloat16(oacc[2][e] * s);
            op[48] = __float2bfloat16(oacc[3][e] * s);
        }
    }
}

// ---------------- time attention (n=16, causal): one block per (b*s, qh) ----------------
__global__ void time_attn_kernel(const bf16* __restrict__ qkv, bf16* __restrict__ ob) {
    __shared__ float qs[16][65], ks[16][65], ps[16][17];
    int bs = blockIdx.x, qh = blockIdx.y, kh = qh >> 1;
    int tid = threadIdx.x;
    size_t rowbase = (size_t)bs * 16;
    #pragma unroll
    for (int i = 0; i < 4; ++i) {
        int idx = tid + 256 * i;
        int r = idx >> 6, d = idx & 63;
        qs[r][d] = __bfloat162float(qkv[(rowbase + r) * 2048 + qh * 64 + d]);
        ks[r][d] = __bfloat162float(qkv[(rowbase + r) * 2048 + 1024 + kh * 64 + d]);
    }
    __syncthreads();
    int i = tid >> 4, j = tid & 15;
    float dot = 0.f;
    #pragma unroll 16
    for (int d = 0; d < 64; ++d) dot += qs[i][d] * ks[j][d];
    float s = dot * 0.125f;
    float x = s * 0.02f;
    float x2 = x * x;
    float v = s * (1.f + x2 * (-0.3333333333f + x2 * 0.1333333333f));
    float p = (j > i) ? 0.f : __expf(v);
    float sum = p;
    sum += __shfl_xor(sum, 1);
    sum += __shfl_xor(sum, 2);
    sum += __shfl_xor(sum, 4);
    sum += __shfl_xor(sum, 8);
    ps[i][j] = p * __builtin_amdgcn_rcpf(sum);
    __syncthreads();
    #pragma unroll
    for (int ii = 0; ii < 4; ++ii) {
        int idx = tid + 256 * ii;
        int r = idx >> 6, d = idx & 63;
        float acc = 0.f;
        #pragma unroll
        for (int jj = 0; jj < 16; ++jj)
            acc += ps[r][jj] * __bfloat162float(qkv[(rowbase + jj) * 2048 + 1536 + kh * 64 + d]);
        ob[(rowbase + r) * 1024 + qh * 64 + d] = __float2bfloat16(acc);
    }
}

// ---------------- host-side launch ----------------
extern "C" void kernel_launch(void* const* d_in, const int* in_sizes, int n_in,
                              void* d_out, int out_size, void* d_ws, size_t ws_size,
                              hipStream_t stream) {
    const float* tokens      = (const float*)d_in[0];
    const float* attn_norm_w = (const float*)d_in[1];
    const float* Wq          = (const float*)d_in[2];
    const float* Wk          = (const float*)d_in[3];
    const float* Wv          = (const float*)d_in[4];
    const float* q_gamma     = (const float*)d_in[5];
    const float* k_gamma     = (const float*)d_in[6];
    const float* Wo          = (const float*)d_in[7];
    const float* ff_norm_w   = (const float*)d_in[8];
    const float* W_in        = (const float*)d_in[9];
    const float* b_in        = (const float*)d_in[10];
    const float* W_out       = (const float*)d_in[11];
    const float* b_out       = (const float*)d_in[12];
    const float* final_w     = (const float*)d_in[13];

    float* x = (float*)d_out;
    char* ws = (char*)d_ws;

    bf16* wtqkv = (bf16*)ws;                     // [2048][512]
    bf16* wto   = wtqkv + 2048 * 512;            // [512][1024]
    bf16* wtin  = wto   + 512 * 1024;            // [2816][512] interleaved
    bf16* wtout = wtin  + 2816 * 512;            // [512][1408]
    size_t off = (size_t)(2048*512 + 512*1024 + 2816*512 + 512*1408) * 2;
    bf16* h = (bf16*)(ws + off);                 // [N][512]
    off += (size_t)NROWS * 512 * 2;
    char* region = ws + off;
    bf16* qkv = (bf16*)region;                               // [N][2048]
    bf16* glu = (bf16*)region;                               // [N][1408] (FF alias)
    bf16* vt  = (bf16*)(region + (size_t)NROWS * 2048 * 2);  // [256][64][288]
    bf16* ob  = (bf16*)(region + (size_t)NROWS * 2048 * 2 + (size_t)256*64*SKP*2);  // [N][1024]

    hipMemcpyAsync(x, tokens, (size_t)NROWS * 512 * 4, hipMemcpyDeviceToDevice, stream);

    for (int l = 0; l < 8; ++l) {
        int is_time = ((l + 1) % 4 == 0) ? 1 : 0;
        wtrans_layer<<<3648, 256, 0, stream>>>(
            Wq + (size_t)l * 512 * 1024, Wk + (size_t)l * 512 * 512,
            Wv + (size_t)l * 512 * 512, Wo + (size_t)l * 1024 * 512,
            W_in + (size_t)l * 512 * DI2, W_out + (size_t)l * DII * 512,
            wtqkv, wto, wtin, wtout);

        // ---- attention block ----
        rms_kernel<1><<<2056, 256, 0, stream>>>(x, attn_norm_w + (size_t)l * 512, h, is_time);
        mfma_gemm_panel<1><<<dim3(16, 16), 512, 0, stream>>>(
            h, 512, wtqkv, 512, nullptr, qkv, 2048, NROWS, 528,
            q_gamma + (size_t)l * 1024, k_gamma + (size_t)l * 512, is_time);
        if (is_time) {
            time_attn_kernel<<<dim3(514, 16), 256, 0, stream>>>(qkv, ob);
            mfma_gemm<3, 1, 64><<<dim3(4, 129), 256, 0, stream>>>(
                ob, 1024, wto, 1024, nullptr, x, 512, 512, NROWS, 1024);
        } else {
            vtrans_kernel<<<dim3(256, 9), 256, 0, stream>>>(qkv, vt);
            space_attn_kernel<<<dim3(5, 16, 32), 256, 0, stream>>>(qkv, vt, ob);
            mfma_gemm<3, 0, 64><<<dim3(4, 129), 256, 0, stream>>>(
                ob, 1024, wto, 1024, nullptr, x, 512, 512, NROWS, 1024);
        }

        // ---- feed-forward block ----
        rms_kernel<1><<<2056, 256, 0, stream>>>(x, ff_norm_w + (size_t)l * 512, h, 0);
        mfma_gemm_panel<2><<<dim3(22, 11), 512, 0, stream>>>(
            h, 512, wtin, 512, b_in + (size_t)l * DI2, glu, GLULD, NROWS, 768,
            nullptr, nullptr, 0);
        mfma_gemm<3, 0, 64><<<dim3(4, 129), 256, 0, stream>>>(
            glu, GLULD, wtout, GLULD, b_out + (size_t)l * 512, x, 512, 512, NROWS, GLULD);
    }

    rms_kernel<0><<<2056, 256, 0, stream>>>(x, final_w, x, 0);
}